// Round 6
// baseline (1172.457 us; speedup 1.0000x reference)
//
#include <hip/hip_runtime.h>

// Problem dims
#define NS 64      // batch
#define TT 256     // caption length
#define TS 255     // RNN timesteps (T-1)
#define VV 10000   // vocab
#define DF 1280    // feature dim
#define WD 256     // word-embed dim
#define HD 512     // hidden dim
#define RTOT (TS*NS)   // 16320 output rows (r = t*64 + n)
#define RPAD 16384     // padded rows for hs

typedef __attribute__((ext_vector_type(4))) float f32x4;
typedef __attribute__((ext_vector_type(8))) short s16x8;
typedef __attribute__((ext_vector_type(4))) unsigned int u32x4;
typedef __attribute__((ext_vector_type(8))) int i32x8;

__device__ __forceinline__ unsigned short f2bf(float f){
  unsigned u; __builtin_memcpy(&u, &f, 4);
  u += 0x7FFFu + ((u >> 16) & 1u);            // RNE
  return (unsigned short)(u >> 16);
}
__device__ __forceinline__ float bf2f(unsigned short h){
  unsigned u = ((unsigned)h) << 16; float f; __builtin_memcpy(&f, &u, 4); return f;
}
__device__ __forceinline__ unsigned char f2fp8(float f){
  int p = __builtin_amdgcn_cvt_pk_fp8_f32(f, f, 0, false);  // OCP e4m3
  return (unsigned char)(p & 0xFF);
}
__device__ __forceinline__ float dot4_fp8(unsigned int a, unsigned int b){
  float d;
  d  = __builtin_amdgcn_cvt_f32_fp8(a, 0) * __builtin_amdgcn_cvt_f32_fp8(b, 0);
  d += __builtin_amdgcn_cvt_f32_fp8(a, 1) * __builtin_amdgcn_cvt_f32_fp8(b, 1);
  d += __builtin_amdgcn_cvt_f32_fp8(a, 2) * __builtin_amdgcn_cvt_f32_fp8(b, 2);
  d += __builtin_amdgcn_cvt_f32_fp8(a, 3) * __builtin_amdgcn_cvt_f32_fp8(b, 3);
  return d;
}
// MX-scaled MFMA, fp8 x fp8, unit scales (e8m0 byte 127 = 2^0) -> exact fp8 GEMM at 2x rate
__device__ __forceinline__ f32x4 mfma128(i32x8 a, i32x8 b, f32x4 c){
  return __builtin_amdgcn_mfma_scale_f32_16x16x128_f8f6f4(a, b, c, 0, 0, 0, 127, 0, 127);
}

// ---------------- K0: transpose + convert weights (fp32 [R][C] -> [C][R] bf16/fp8)
template<int FP8>
__global__ __launch_bounds__(256) void k_transpose_cvt(const float* __restrict__ src,
    unsigned char* __restrict__ dst, int R, int C){
  __shared__ float tile[32][33];
  int r0 = blockIdx.x*32, c0 = blockIdx.y*32;
  int tr = threadIdx.x >> 5, tc = threadIdx.x & 31;
  #pragma unroll
  for(int p=0;p<4;p++){
    int r = r0 + tr + p*8, c = c0 + tc;
    tile[tr + p*8][tc] = (r < R && c < C) ? src[r*C + c] : 0.f;
  }
  __syncthreads();
  #pragma unroll
  for(int p=0;p<4;p++){
    int oc = c0 + tr + p*8;   // dst row (C dim)
    int orow = r0 + tc;       // dst col (R dim)
    if(oc < C && orow < R){
      float v = tile[tc][tr + p*8];
      if(FP8) dst[oc*R + orow] = f2fp8(v);
      else ((unsigned short*)dst)[oc*R + orow] = f2bf(v);
    }
  }
}

// ---------------- K0w: Wh fp32 [k][j] -> Wh8S wave-order K=128-frag fp8.
// Byte i: blk=i>>11 -> w=blk>>4, ct=(blk>>2)&3, kq=blk&3; lane=(i>>5)&63, ib=i&31;
// q=lane>>4, rr=lane&15; k=kq*128+q*32+ib; j=w*64+ct*16+rr.
// Each (w,ct,kq) 2048-B block = one wave's B-frag (i32x8/lane), fully coalesced.
__global__ __launch_bounds__(256) void k_cvt_whS(const float* __restrict__ Wh,
    unsigned char* __restrict__ Wh8S){
  int i = blockIdx.x*256 + threadIdx.x;      // 1024 blocks -> 256K bytes
  int blk = i>>11;
  int w = blk>>4, ct = (blk>>2)&3, kq = blk&3;
  int lane = (i>>5)&63, ib = i&31;
  int q = lane>>4, rr = lane&15;
  int k = kq*128 + q*32 + ib;
  int j = w*64 + ct*16 + rr;
  Wh8S[i] = f2fp8(Wh[k*HD + j]);
}

// ---------------- K0c: elementwise fp32 -> bf16
__global__ __launch_bounds__(256) void k_cvt_bf16(const float* __restrict__ src,
    unsigned short* __restrict__ dst, int n){
  int i = blockIdx.x*256 + threadIdx.x;
  if(i < n) dst[i] = f2bf(src[i]);
}

// ---------------- K1: h0 = feat @ W_proj + b_proj  -> bf16 [64][512]
__global__ __launch_bounds__(256) void k_h0(const unsigned short* __restrict__ featb,
    const unsigned short* __restrict__ WprojT, const float* __restrict__ b_proj,
    unsigned short* __restrict__ h0b){
  __shared__ unsigned short Al[64*264];
  __shared__ unsigned short Bl[64*264];
  int tid = threadIdx.x, cb = blockIdx.x;
  int w = tid>>6, lane = tid&63, q = lane>>4, rr = lane&15;
  f32x4 acc[4];
  #pragma unroll
  for(int i=0;i<4;i++){ acc[i][0]=0.f; acc[i][1]=0.f; acc[i][2]=0.f; acc[i][3]=0.f; }
  for(int kb=0; kb<5; kb++){
    {
      int row = tid >> 2, part = tid & 3;
      const u32x4* s = (const u32x4*)(featb + row*DF + kb*256 + part*64);
      u32x4* d = (u32x4*)(Al + row*264 + part*64);
      #pragma unroll
      for(int i=0;i<8;i++) d[i] = s[i];
    }
    {
      int row = tid >> 2, part = tid & 3;
      int j = cb*64 + row;
      const u32x4* s = (const u32x4*)(WprojT + j*DF + kb*256 + part*64);
      u32x4* d = (u32x4*)(Bl + row*264 + part*64);
      #pragma unroll
      for(int i=0;i<8;i++) d[i] = s[i];
    }
    __syncthreads();
    #pragma unroll
    for(int kc=0;kc<8;kc++){
      s16x8 a = *(const s16x8*)(Al + (w*16 + rr)*264 + kc*32 + q*8);
      #pragma unroll
      for(int tc=0;tc<4;tc++){
        s16x8 bb = *(const s16x8*)(Bl + (tc*16 + rr)*264 + kc*32 + q*8);
        acc[tc] = __builtin_amdgcn_mfma_f32_16x16x32_bf16(a, bb, acc[tc], 0, 0, 0);
      }
    }
    __syncthreads();
  }
  #pragma unroll
  for(int tc=0;tc<4;tc++){
    #pragma unroll
    for(int reg=0;reg<4;reg++){
      int n = w*16 + q*4 + reg;
      int j = cb*64 + tc*16 + rr;
      h0b[n*HD + j] = f2bf(acc[tc][reg] + b_proj[j]);
    }
  }
}

// ---------------- K2: xW[t][n][j] = W_embed[cap[n][t]] @ Wx + b  -> bf16
__global__ __launch_bounds__(256) void k_xw(const unsigned short* __restrict__ Wembb,
    const unsigned short* __restrict__ WxT, const float* __restrict__ bvec,
    const int* __restrict__ captions, unsigned short* __restrict__ xWb){
  __shared__ unsigned short Al[64*264];
  __shared__ unsigned short Bl[64*264];
  int tid = threadIdx.x, cb = blockIdx.x, t = blockIdx.y;
  int w = tid>>6, lane = tid&63, q = lane>>4, rr = lane&15;
  {
    int row = tid >> 2, part = tid & 3;
    int idx = captions[row*TT + t];
    const u32x4* s = (const u32x4*)(Wembb + idx*WD + part*64);
    u32x4* d = (u32x4*)(Al + row*264 + part*64);
    #pragma unroll
    for(int i=0;i<8;i++) d[i] = s[i];
  }
  {
    int row = tid >> 2, part = tid & 3;
    int j = cb*64 + row;
    const u32x4* s = (const u32x4*)(WxT + j*WD + part*64);
    u32x4* d = (u32x4*)(Bl + row*264 + part*64);
    #pragma unroll
    for(int i=0;i<8;i++) d[i] = s[i];
  }
  __syncthreads();
  f32x4 acc[4];
  #pragma unroll
  for(int i=0;i<4;i++){ acc[i][0]=0.f; acc[i][1]=0.f; acc[i][2]=0.f; acc[i][3]=0.f; }
  #pragma unroll
  for(int kc=0;kc<8;kc++){
    s16x8 a = *(const s16x8*)(Al + (w*16 + rr)*264 + kc*32 + q*8);
    #pragma unroll
    for(int tc=0;tc<4;tc++){
      s16x8 bb = *(const s16x8*)(Bl + (tc*16 + rr)*264 + kc*32 + q*8);
      acc[tc] = __builtin_amdgcn_mfma_f32_16x16x32_bf16(a, bb, acc[tc], 0, 0, 0);
    }
  }
  #pragma unroll
  for(int tc=0;tc<4;tc++){
    #pragma unroll
    for(int reg=0;reg<4;reg++){
      int n = w*16 + q*4 + reg;
      int j = cb*64 + tc*16 + rr;
      xWb[t*(NS*HD) + n*HD + j] = f2bf(acc[tc][reg] + bvec[j]);
    }
  }
}

// ---------------- K3: RNN scan, K=128 MX-fp8 MFMA (2x rate). Wh: ct 0,1 slabs in LDS,
// ct 2,3 streamed L2->VGPR coalesced. h fp8 dbuf in LDS; hs8 written 16B/thread.
__global__ __launch_bounds__(512, 2) void k_rnn(const unsigned short* __restrict__ h0b,
    const unsigned char* __restrict__ Wh8S, const unsigned short* __restrict__ xWb,
    unsigned char* __restrict__ hs8){
  __shared__ unsigned char whl[131072];        // ct=0,1 slabs, wave-frag order
  __shared__ unsigned char hbuf[2][16*560];    // fp8 h, stride 560 (16-aligned)
  int tid = threadIdx.x, w = tid>>6, lane = tid&63, q = lane>>4, rr = lane&15;
  int n0 = blockIdx.x * 16;
  int j0 = w * 64;
  // preload LDS half of Wh: LDS block l=(w*2+ct)*4+kq  <-  global block (w*4+ct)*4+kq
  #pragma unroll
  for(int i=0;i<16;i++){
    int o = (i*512 + tid)*16;
    int l = o >> 11;
    int gblk = ((l>>3)*4 + ((l>>2)&1))*4 + (l&3);
    *(u32x4*)(whl + o) = *(const u32x4*)(Wh8S + gblk*2048 + (o & 2047));
  }
  // init h (bf16 -> fp8) into hbuf[0]
  {
    int s = tid>>5, c0 = (tid&31)*16;
    #pragma unroll
    for(int i=0;i<16;i++)
      hbuf[0][s*560 + c0 + i] = f2fp8(bf2f(h0b[(n0+s)*HD + c0 + i]));
  }
  __syncthreads();
  const unsigned short* xwp = xWb + n0*HD;
  int scp = tid>>5, scc = (tid&31)*16;         // hs8 store coords
  for(int t=0; t<TS; t++){
    const unsigned char* hb = hbuf[t&1];
    unsigned char*       hn = hbuf[(t&1)^1];
    // write h_t (this step's input) to hs8 at index t-1 (h_1..h_254 here; h_255 after loop)
    if(t)
      *(u32x4*)(hs8 + (size_t)((t-1)*NS + n0 + scp)*HD + scc) = *(const u32x4*)(hb + scp*560 + scc);
    // streamed B frags (ct=2,3): 1KB/wave per b128, fully coalesced
    i32x8 ws2[4], ws3[4];
    #pragma unroll
    for(int kq=0;kq<4;kq++)
      ws2[kq] = *(const i32x8*)(Wh8S + (size_t)(((w*4+2)*4+kq))*2048 + lane*32);
    #pragma unroll
    for(int kq=0;kq<4;kq++)
      ws3[kq] = *(const i32x8*)(Wh8S + (size_t)(((w*4+3)*4+kq))*2048 + lane*32);
    // A frags (K=128: lane holds k = q*32..q*32+32 within each kq chunk)
    i32x8 af[4];
    #pragma unroll
    for(int kq=0;kq<4;kq++)
      af[kq] = *(const i32x8*)(hb + rr*560 + kq*128 + q*32);
    // xw for this step
    float xwv[16];
    #pragma unroll
    for(int ct=0;ct<4;ct++)
      #pragma unroll
      for(int reg=0;reg<4;reg++)
        xwv[ct*4+reg] = bf2f(xwp[(q*4+reg)*HD + j0 + ct*16 + rr]);
    f32x4 acc[4];
    #pragma unroll
    for(int ct=0;ct<4;ct++){ acc[ct][0]=0.f; acc[ct][1]=0.f; acc[ct][2]=0.f; acc[ct][3]=0.f; }
    // LDS-resident cts (0,1)
    #pragma unroll
    for(int ct=0;ct<2;ct++)
      #pragma unroll
      for(int kq=0;kq<4;kq++){
        i32x8 bv = *(const i32x8*)(whl + (size_t)((w*2+ct)*4+kq)*2048 + lane*32);
        acc[ct] = mfma128(af[kq], bv, acc[ct]);
      }
    // streamed cts (2,3)
    #pragma unroll
    for(int kq=0;kq<4;kq++) acc[2] = mfma128(af[kq], ws2[kq], acc[2]);
    #pragma unroll
    for(int kq=0;kq<4;kq++) acc[3] = mfma128(af[kq], ws3[kq], acc[3]);
    #pragma unroll
    for(int ct=0;ct<4;ct++){
      int j = j0 + ct*16 + rr;
      #pragma unroll
      for(int reg=0;reg<4;reg++){
        int nl = q*4 + reg;
        float pre = acc[ct][reg] + xwv[ct*4+reg];
        float e2 = __builtin_amdgcn_exp2f(pre * 2.8853900817779268f); // e^(2x)
        float h = (e2 - 1.f) * __builtin_amdgcn_rcpf(e2 + 1.f);       // tanh
        hn[nl*560 + j] = f2fp8(h);
      }
    }
    __syncthreads();
    xwp += NS*HD;
  }
  // final store: h_255 lives in hbuf[1] (TS odd)
  *(u32x4*)(hs8 + (size_t)((TS-1)*NS + n0 + scp)*HD + scc) = *(const u32x4*)(hbuf[TS&1] + scp*560 + scc);
}

// ---------------- K4: fused scores GEMM (MX-fp8 K=128) + sumexp partials.
// grid (4 chunks, 256 rowblocks of 64); 256 thr; 64-row B tiles -> 4 blocks/CU.
__global__ __launch_bounds__(256, 4) void k_scores(const unsigned char* __restrict__ hs8,
    const unsigned char* __restrict__ WoutT, const float* __restrict__ b_out,
    float* __restrict__ partial_s){
  __shared__ unsigned char Bl[64*528];
  __shared__ float sred[2][64];
  int tid = threadIdx.x;
  int chunk = blockIdx.x, rb = blockIdx.y;
  int w = tid>>6, lane = tid&63, q = lane>>4, rr = lane&15;
  int wi = w>>1, wj = w&1;          // wi: row half (32), wj: col half (32)
  i32x8 af[2][4];
  #pragma unroll
  for(int tr=0;tr<2;tr++)
    #pragma unroll
    for(int kq=0;kq<4;kq++){
      int row = rb*64 + wi*32 + tr*16 + rr;   // < RPAD always
      af[tr][kq] = *(const i32x8*)(hs8 + (size_t)row*HD + kq*128 + q*32);
    }
  float sacc[8];
  #pragma unroll
  for(int i=0;i<8;i++) sacc[i]=0.f;
  int vc0 = chunk*2500, vc1 = vc0 + 2500;
  for(int vt=0; vt<40; vt++){
    int vbase = vc0 + vt*64;
    {
      int v = tid & 63, part = tid >> 6;
      int vg = vbase + v; if(vg > VV-1) vg = VV-1;
      const u32x4* s = (const u32x4*)(WoutT + (size_t)vg*HD + part*128);
      u32x4 t0=s[0],t1=s[1],t2=s[2],t3=s[3],t4=s[4],t5=s[5],t6=s[6],t7=s[7];
      u32x4* d = (u32x4*)(Bl + v*528 + part*128);
      d[0]=t0;d[1]=t1;d[2]=t2;d[3]=t3;d[4]=t4;d[5]=t5;d[6]=t6;d[7]=t7;
    }
    __syncthreads();
    f32x4 acc[2][2];
    #pragma unroll
    for(int a=0;a<2;a++)
      #pragma unroll
      for(int b=0;b<2;b++){ acc[a][b][0]=0.f; acc[a][b][1]=0.f; acc[a][b][2]=0.f; acc[a][b][3]=0.f; }
    #pragma unroll
    for(int kq=0;kq<4;kq++){
      i32x8 b0 = *(const i32x8*)(Bl + (wj*32 +  0 + rr)*528 + kq*128 + q*32);
      i32x8 b1 = *(const i32x8*)(Bl + (wj*32 + 16 + rr)*528 + kq*128 + q*32);
      acc[0][0] = mfma128(af[0][kq], b0, acc[0][0]);
      acc[0][1] = mfma128(af[0][kq], b1, acc[0][1]);
      acc[1][0] = mfma128(af[1][kq], b0, acc[1][0]);
      acc[1][1] = mfma128(af[1][kq], b1, acc[1][1]);
    }
    #pragma unroll
    for(int tc=0;tc<2;tc++){
      int vg = vbase + wj*32 + tc*16 + rr;
      bool vok = vg < vc1;
      float bo = vok ? b_out[vg] : 0.f;
      #pragma unroll
      for(int tr=0;tr<2;tr++)
        #pragma unroll
        for(int reg=0;reg<4;reg++){
          float sc = acc[tr][tc][reg] + bo;
          float ex = __builtin_amdgcn_exp2f(sc * 1.4426950408889634f);
          if(vok) sacc[tr*4+reg] += ex;
        }
    }
    __syncthreads();
  }
  #pragma unroll
  for(int i=0;i<8;i++){
    float v = sacc[i];
    v += __shfl_xor(v, 1, 64);
    v += __shfl_xor(v, 2, 64);
    v += __shfl_xor(v, 4, 64);
    v += __shfl_xor(v, 8, 64);
    sacc[i] = v;
  }
  if(rr == 0){
    #pragma unroll
    for(int tr=0;tr<2;tr++)
      #pragma unroll
      for(int reg=0;reg<4;reg++)
        sred[wj][wi*32 + tr*16 + q*4 + reg] = sacc[tr*4+reg];
  }
  __syncthreads();
  if(tid < 64){
    int row = rb*64 + tid;
    if(row < RTOT) partial_s[row*4 + chunk] = sred[0][tid] + sred[1][tid];
  }
}

// ---------------- K4b: picked[R] = score(R, y_R) ; one wave per row
__global__ __launch_bounds__(256) void k_picked(const unsigned char* __restrict__ hs8,
    const unsigned char* __restrict__ WoutT, const float* __restrict__ b_out,
    const int* __restrict__ captions, float* __restrict__ picked){
  int tid = threadIdx.x;
  int w = tid>>6, lane = tid&63;
  int R = blockIdx.x*4 + w;                 // 4080*4 = 16320 exact
  int t = R >> 6, n = R & 63;
  int y = captions[n*TT + t + 1];
  const unsigned int* hp = (const unsigned int*)(hs8 + (size_t)R*HD + lane*8);
  const unsigned int* wp = (const unsigned int*)(WoutT + (size_t)y*HD + lane*8);
  unsigned int hv0 = hp[0], hv1 = hp[1], wv0 = wp[0], wv1 = wp[1];
  float d = dot4_fp8(hv0, wv0) + dot4_fp8(hv1, wv1);
  d += __shfl_xor(d, 1, 64);
  d += __shfl_xor(d, 2, 64);
  d += __shfl_xor(d, 4, 64);
  d += __shfl_xor(d, 8, 64);
  d += __shfl_xor(d, 16, 64);
  d += __shfl_xor(d, 32, 64);
  if(lane == 0) picked[R] = d + b_out[y];
}

// ---------------- K5: loss = sum_masked(log(sum_s) - picked) / 64
__global__ __launch_bounds__(256) void k_loss(const float* __restrict__ partial_s,
    const float* __restrict__ picked, const int* __restrict__ captions,
    float* __restrict__ out){
  int tid = threadIdx.x;
  float a = 0.f;
  for(int R = tid; R < RTOT; R += 256){
    int t = R >> 6, n = R & 63;
    int y = captions[n*TT + t + 1];
    if(y != 0){
      float s = partial_s[R*4] + partial_s[R*4+1] + partial_s[R*4+2] + partial_s[R*4+3];
      a += __logf(s) - picked[R];
    }
  }
  a += __shfl_xor(a, 1, 64);
  a += __shfl_xor(a, 2, 64);
  a += __shfl_xor(a, 4, 64);
  a += __shfl_xor(a, 8, 64);
  a += __shfl_xor(a, 16, 64);
  a += __shfl_xor(a, 32, 64);
  __shared__ float red[4];
  int w = tid>>6, lane = tid&63;
  if(lane == 0) red[w] = a;
  __syncthreads();
  if(tid == 0) out[0] = (red[0]+red[1]+red[2]+red[3]) * (1.0f/64.0f);
}

extern "C" void kernel_launch(void* const* d_in, const int* in_sizes, int n_in,
                              void* d_out, int out_size, void* d_ws, size_t ws_size,
                              hipStream_t stream) {
  const float* feat    = (const float*)d_in[0];
  const float* W_proj  = (const float*)d_in[1];
  const float* b_proj  = (const float*)d_in[2];
  const float* W_embed = (const float*)d_in[3];
  const float* Wx      = (const float*)d_in[4];
  const float* Wh      = (const float*)d_in[5];
  const float* bvec    = (const float*)d_in[6];
  const float* W_out   = (const float*)d_in[7];
  const float* b_out   = (const float*)d_in[8];
  const int*   captions= (const int*)d_in[9];

  char* p = (char*)d_ws;
  unsigned short* WprojT = (unsigned short*)p;  p += 512*1280*2;    // 1,310,720
  unsigned short* WxT    = (unsigned short*)p;  p += 512*256*2;     //   262,144
  unsigned char*  Wh8S   = (unsigned char*)p;   p += 512*512;       //   262,144
  unsigned char*  WoutT  = (unsigned char*)p;   p += 10000*512;     // 5,120,000
  unsigned short* Wembb  = (unsigned short*)p;  p += 10000*256*2;   // 5,120,000
  unsigned short* featb  = (unsigned short*)p;  p += 64*1280*2;     //   163,840
  unsigned short* h0b    = (unsigned short*)p;  p += 64*512*2;      //    65,536
  unsigned short* xWb    = (unsigned short*)p;  p += TS*64*512*2;   //16,711,680
  unsigned char*  hs8    = (unsigned char*)p;   p += RPAD*512;      // 8,388,608
  float* partial_s       = (float*)p;           p += RTOT*4*4;      //   261,120
  float* picked          = (float*)p;           p += RTOT*4;        //    65,280
  if((size_t)(p - (char*)d_ws) > ws_size) return;  // workspace too small

  // K0: weight conversions
  k_transpose_cvt<0><<<dim3(40,16), 256, 0, stream>>>(W_proj, (unsigned char*)WprojT, 1280, 512);
  k_transpose_cvt<0><<<dim3(8,16),  256, 0, stream>>>(Wx,     (unsigned char*)WxT,    256,  512);
  k_cvt_whS<<<1024, 256, 0, stream>>>(Wh, Wh8S);
  k_transpose_cvt<1><<<dim3(16,313),256, 0, stream>>>(W_out,  WoutT,                  512,  10000);
  k_cvt_bf16<<<320,   256, 0, stream>>>(feat,    featb, 64*1280);
  k_cvt_bf16<<<10000, 256, 0, stream>>>(W_embed, Wembb, 10000*256);

  // K1: h0
  k_h0<<<8, 256, 0, stream>>>(featb, WprojT, b_proj, h0b);
  // K2: xW
  k_xw<<<dim3(8, TS), 256, 0, stream>>>(Wembb, WxT, bvec, captions, xWb);
  // K3: RNN scan (K=128 MX-fp8; Wh half LDS-resident, half streamed)
  k_rnn<<<4, 512, 0, stream>>>(h0b, Wh8S, xWb, hs8);
  // K4: fused scores + sumexp partials (K=128 MX-fp8)
  k_scores<<<dim3(4, 256), 256, 0, stream>>>(hs8, WoutT, b_out, partial_s);
  // K4b: picked scores
  k_picked<<<4080, 256, 0, stream>>>(hs8, WoutT, b_out, captions, picked);
  // K5: final loss
  k_loss<<<1, 256, 0, stream>>>(partial_s, picked, captions, (float*)d_out);
}

// Round 7
// 856.369 us; speedup vs baseline: 1.3691x; 1.3691x over previous
//
#include <hip/hip_runtime.h>

// Problem dims
#define NS 64      // batch
#define TT 256     // caption length
#define TS 255     // RNN timesteps (T-1)
#define VV 10000   // vocab
#define DF 1280    // feature dim
#define WD 256     // word-embed dim
#define HD 512     // hidden dim
#define RTOT (TS*NS)   // 16320 output rows (r = t*64 + n)
#define RPAD 16384     // padded rows for hs

typedef __attribute__((ext_vector_type(4))) float f32x4;
typedef __attribute__((ext_vector_type(8))) short s16x8;
typedef __attribute__((ext_vector_type(4))) unsigned int u32x4;
typedef __attribute__((ext_vector_type(8))) int i32x8;

__device__ __forceinline__ unsigned short f2bf(float f){
  unsigned u; __builtin_memcpy(&u, &f, 4);
  u += 0x7FFFu + ((u >> 16) & 1u);            // RNE
  return (unsigned short)(u >> 16);
}
__device__ __forceinline__ float bf2f(unsigned short h){
  unsigned u = ((unsigned)h) << 16; float f; __builtin_memcpy(&f, &u, 4); return f;
}
__device__ __forceinline__ unsigned char f2fp8(float f){
  int p = __builtin_amdgcn_cvt_pk_fp8_f32(f, f, 0, false);  // OCP e4m3
  return (unsigned char)(p & 0xFF);
}
__device__ __forceinline__ float dot4_fp8(unsigned int a, unsigned int b){
  float d;
  d  = __builtin_amdgcn_cvt_f32_fp8(a, 0) * __builtin_amdgcn_cvt_f32_fp8(b, 0);
  d += __builtin_amdgcn_cvt_f32_fp8(a, 1) * __builtin_amdgcn_cvt_f32_fp8(b, 1);
  d += __builtin_amdgcn_cvt_f32_fp8(a, 2) * __builtin_amdgcn_cvt_f32_fp8(b, 2);
  d += __builtin_amdgcn_cvt_f32_fp8(a, 3) * __builtin_amdgcn_cvt_f32_fp8(b, 3);
  return d;
}
// MX-scaled MFMA, fp8 x fp8, unit scales -> exact fp8 GEMM at 2x rate (verified r6, absmax 0.0)
__device__ __forceinline__ f32x4 mfma128(i32x8 a, i32x8 b, f32x4 c){
  return __builtin_amdgcn_mfma_scale_f32_16x16x128_f8f6f4(a, b, c, 0, 0, 0, 127, 0, 127);
}

// ---------------- K0: transpose + convert weights (fp32 [R][C] -> [C][R] bf16/fp8)
template<int FP8>
__global__ __launch_bounds__(256) void k_transpose_cvt(const float* __restrict__ src,
    unsigned char* __restrict__ dst, int R, int C){
  __shared__ float tile[32][33];
  int r0 = blockIdx.x*32, c0 = blockIdx.y*32;
  int tr = threadIdx.x >> 5, tc = threadIdx.x & 31;
  #pragma unroll
  for(int p=0;p<4;p++){
    int r = r0 + tr + p*8, c = c0 + tc;
    tile[tr + p*8][tc] = (r < R && c < C) ? src[r*C + c] : 0.f;
  }
  __syncthreads();
  #pragma unroll
  for(int p=0;p<4;p++){
    int oc = c0 + tr + p*8;   // dst row (C dim)
    int orow = r0 + tc;       // dst col (R dim)
    if(oc < C && orow < R){
      float v = tile[tc][tr + p*8];
      if(FP8) dst[oc*R + orow] = f2fp8(v);
      else ((unsigned short*)dst)[oc*R + orow] = f2bf(v);
    }
  }
}

// ---------------- K0w: Wh fp32 [k][j] -> Wh8S wave-order K=128-frag fp8.
__global__ __launch_bounds__(256) void k_cvt_whS(const float* __restrict__ Wh,
    unsigned char* __restrict__ Wh8S){
  int i = blockIdx.x*256 + threadIdx.x;      // 1024 blocks -> 256K bytes
  int blk = i>>11;
  int w = blk>>4, ct = (blk>>2)&3, kq = blk&3;
  int lane = (i>>5)&63, ib = i&31;
  int q = lane>>4, rr = lane&15;
  int k = kq*128 + q*32 + ib;
  int j = w*64 + ct*16 + rr;
  Wh8S[i] = f2fp8(Wh[k*HD + j]);
}

// ---------------- K0c: elementwise fp32 -> bf16
__global__ __launch_bounds__(256) void k_cvt_bf16(const float* __restrict__ src,
    unsigned short* __restrict__ dst, int n){
  int i = blockIdx.x*256 + threadIdx.x;
  if(i < n) dst[i] = f2bf(src[i]);
}

// ---------------- K1: h0 = feat @ W_proj + b_proj  -> bf16 [64][512]
__global__ __launch_bounds__(256) void k_h0(const unsigned short* __restrict__ featb,
    const unsigned short* __restrict__ WprojT, const float* __restrict__ b_proj,
    unsigned short* __restrict__ h0b){
  __shared__ unsigned short Al[64*264];
  __shared__ unsigned short Bl[64*264];
  int tid = threadIdx.x, cb = blockIdx.x;
  int w = tid>>6, lane = tid&63, q = lane>>4, rr = lane&15;
  f32x4 acc[4];
  #pragma unroll
  for(int i=0;i<4;i++){ acc[i][0]=0.f; acc[i][1]=0.f; acc[i][2]=0.f; acc[i][3]=0.f; }
  for(int kb=0; kb<5; kb++){
    {
      int row = tid >> 2, part = tid & 3;
      const u32x4* s = (const u32x4*)(featb + row*DF + kb*256 + part*64);
      u32x4* d = (u32x4*)(Al + row*264 + part*64);
      #pragma unroll
      for(int i=0;i<8;i++) d[i] = s[i];
    }
    {
      int row = tid >> 2, part = tid & 3;
      int j = cb*64 + row;
      const u32x4* s = (const u32x4*)(WprojT + j*DF + kb*256 + part*64);
      u32x4* d = (u32x4*)(Bl + row*264 + part*64);
      #pragma unroll
      for(int i=0;i<8;i++) d[i] = s[i];
    }
    __syncthreads();
    #pragma unroll
    for(int kc=0;kc<8;kc++){
      s16x8 a = *(const s16x8*)(Al + (w*16 + rr)*264 + kc*32 + q*8);
      #pragma unroll
      for(int tc=0;tc<4;tc++){
        s16x8 bb = *(const s16x8*)(Bl + (tc*16 + rr)*264 + kc*32 + q*8);
        acc[tc] = __builtin_amdgcn_mfma_f32_16x16x32_bf16(a, bb, acc[tc], 0, 0, 0);
      }
    }
    __syncthreads();
  }
  #pragma unroll
  for(int tc=0;tc<4;tc++){
    #pragma unroll
    for(int reg=0;reg<4;reg++){
      int n = w*16 + q*4 + reg;
      int j = cb*64 + tc*16 + rr;
      h0b[n*HD + j] = f2bf(acc[tc][reg] + b_proj[j]);
    }
  }
}

// ---------------- K2: xW + b -> xWk in K3-thread-major layout.
__global__ __launch_bounds__(256) void k_xw(const unsigned short* __restrict__ Wembb,
    const unsigned short* __restrict__ WxT, const float* __restrict__ bvec,
    const int* __restrict__ captions, unsigned short* __restrict__ xWk){
  __shared__ unsigned short Al[64*264];
  __shared__ unsigned short Bl[64*264];
  int tid = threadIdx.x, cb = blockIdx.x, t = blockIdx.y;
  int w = tid>>6, lane = tid&63, q = lane>>4, rr = lane&15;
  {
    int row = tid >> 2, part = tid & 3;
    int idx = captions[row*TT + t];
    const u32x4* s = (const u32x4*)(Wembb + idx*WD + part*64);
    u32x4* d = (u32x4*)(Al + row*264 + part*64);
    #pragma unroll
    for(int i=0;i<8;i++) d[i] = s[i];
  }
  {
    int row = tid >> 2, part = tid & 3;
    int j = cb*64 + row;
    const u32x4* s = (const u32x4*)(WxT + j*WD + part*64);
    u32x4* d = (u32x4*)(Bl + row*264 + part*64);
    #pragma unroll
    for(int i=0;i<8;i++) d[i] = s[i];
  }
  __syncthreads();
  f32x4 acc[4];
  #pragma unroll
  for(int i=0;i<4;i++){ acc[i][0]=0.f; acc[i][1]=0.f; acc[i][2]=0.f; acc[i][3]=0.f; }
  #pragma unroll
  for(int kc=0;kc<8;kc++){
    s16x8 a = *(const s16x8*)(Al + (w*16 + rr)*264 + kc*32 + q*8);
    #pragma unroll
    for(int tc=0;tc<4;tc++){
      s16x8 bb = *(const s16x8*)(Bl + (tc*16 + rr)*264 + kc*32 + q*8);
      acc[tc] = __builtin_amdgcn_mfma_f32_16x16x32_bf16(a, bb, acc[tc], 0, 0, 0);
    }
  }
  #pragma unroll
  for(int tc=0;tc<4;tc++){
    int j = cb*64 + tc*16 + rr;
    float bo = bvec[j];
    unsigned short st[4];
    #pragma unroll
    for(int reg=0;reg<4;reg++)
      st[reg] = f2bf(acc[tc][reg] + bo);
    size_t f = (((size_t)t*4 + w)*8 + cb)*1024 + q*256 + rr*16 + tc*4;
    unsigned long v; __builtin_memcpy(&v, st, 8);
    *(unsigned long*)(xWk + f) = v;
  }
}

// ---------------- K3: RNN scan. ALL Wh B-frags resident in VGPRs (128/thread).
__global__ __launch_bounds__(512, 2) void k_rnn(const unsigned short* __restrict__ h0b,
    const unsigned char* __restrict__ Wh8S, const unsigned short* __restrict__ xWk,
    unsigned char* __restrict__ hs8){
  __shared__ unsigned char hbuf[2][16*560];    // fp8 h, stride 560
  int tid = threadIdx.x, w = tid>>6, lane = tid&63, q = lane>>4, rr = lane&15;
  int n0 = blockIdx.x * 16;
  int j0 = w * 64;
  i32x8 wb[16];
  #pragma unroll
  for(int ct=0;ct<4;ct++)
    #pragma unroll
    for(int kq=0;kq<4;kq++)
      wb[ct*4+kq] = *(const i32x8*)(Wh8S + (size_t)((w*4+ct)*4+kq)*2048 + lane*32);
  {
    int s = tid>>5, c0 = (tid&31)*16;
    #pragma unroll
    for(int i=0;i<16;i++)
      hbuf[0][s*560 + c0 + i] = f2fp8(bf2f(h0b[(n0+s)*HD + c0 + i]));
  }
  __syncthreads();
  int scp = tid>>5, scc = (tid&31)*16;
  const unsigned short* xp = xWk + (((size_t)blockIdx.x)*8 + w)*1024 + q*256 + rr*16;
  for(int t=0; t<TS; t++){
    const unsigned char* hb = hbuf[t&1];
    unsigned char*       hn = hbuf[(t&1)^1];
    if(t)
      *(u32x4*)(hs8 + (size_t)((t-1)*NS + n0 + scp)*HD + scc) = *(const u32x4*)(hb + scp*560 + scc);
    unsigned short xs[16];
    *(u32x4*)(xs)   = *(const u32x4*)(xp);
    *(u32x4*)(xs+8) = *(const u32x4*)(xp+8);
    i32x8 af[4];
    #pragma unroll
    for(int kq=0;kq<4;kq++)
      af[kq] = *(const i32x8*)(hb + rr*560 + kq*128 + q*32);
    f32x4 acc[4];
    #pragma unroll
    for(int ct=0;ct<4;ct++){ acc[ct][0]=0.f; acc[ct][1]=0.f; acc[ct][2]=0.f; acc[ct][3]=0.f; }
    #pragma unroll
    for(int ct=0;ct<4;ct++)
      #pragma unroll
      for(int kq=0;kq<4;kq++)
        acc[ct] = mfma128(af[kq], wb[ct*4+kq], acc[ct]);
    #pragma unroll
    for(int ct=0;ct<4;ct++){
      int j = j0 + ct*16 + rr;
      #pragma unroll
      for(int reg=0;reg<4;reg++){
        int nl = q*4 + reg;
        float pre = acc[ct][reg] + bf2f(xs[ct*4+reg]);
        float e2 = __builtin_amdgcn_exp2f(pre * 2.8853900817779268f); // e^(2x)
        float h = (e2 - 1.f) * __builtin_amdgcn_rcpf(e2 + 1.f);       // tanh
        hn[nl*560 + j] = f2fp8(h);
      }
    }
    __syncthreads();
    xp += 32768;
  }
  *(u32x4*)(hs8 + (size_t)((TS-1)*NS + n0 + scp)*HD + scc) = *(const u32x4*)(hbuf[TS&1] + scp*560 + scc);
}

// ---------------- K4: fused scores GEMM (MX-fp8 K=128) + sumexp partials.
__global__ __launch_bounds__(256, 2) void k_scores(const unsigned char* __restrict__ hs8,
    const unsigned char* __restrict__ WoutT, const float* __restrict__ b_out,
    float* __restrict__ partial_s){
  __shared__ unsigned char Bl[128*528];
  __shared__ float sred[2][128];
  int tid = threadIdx.x;
  int chunk = blockIdx.x, rb = blockIdx.y;
  int w = tid>>6, lane = tid&63, q = lane>>4, rr = lane&15;
  int wi = w>>1, wj = w&1;
  i32x8 af[4][4];
  #pragma unroll
  for(int tr=0;tr<4;tr++)
    #pragma unroll
    for(int kq=0;kq<4;kq++){
      int row = rb*128 + wi*64 + tr*16 + rr;
      af[tr][kq] = *(const i32x8*)(hs8 + (size_t)row*HD + kq*128 + q*32);
    }
  float sacc[16];
  #pragma unroll
  for(int i=0;i<16;i++) sacc[i]=0.f;
  int vc0 = chunk*2500, vc1 = vc0 + 2500;
  for(int vt=0; vt<20; vt++){
    int vbase = vc0 + vt*128;
    {
      int v = tid>>1, half = tid&1;
      int vg = vbase + v; if(vg > VV-1) vg = VV-1;
      const u32x4* s = (const u32x4*)(WoutT + (size_t)vg*HD + half*256);
      u32x4* d = (u32x4*)(Bl + v*528 + half*256);
      #pragma unroll
      for(int i=0;i<16;i++) d[i] = s[i];
    }
    __syncthreads();
    #pragma unroll
    for(int hf=0; hf<2; hf++){
      f32x4 acc[4][2];
      #pragma unroll
      for(int a=0;a<4;a++)
        #pragma unroll
        for(int b=0;b<2;b++){ acc[a][b][0]=0.f; acc[a][b][1]=0.f; acc[a][b][2]=0.f; acc[a][b][3]=0.f; }
      #pragma unroll
      for(int kq=0;kq<4;kq++){
        i32x8 b0 = *(const i32x8*)(Bl + (wj*64 + (hf*2  )*16 + rr)*528 + kq*128 + q*32);
        i32x8 b1 = *(const i32x8*)(Bl + (wj*64 + (hf*2+1)*16 + rr)*528 + kq*128 + q*32);
        #pragma unroll
        for(int tr=0;tr<4;tr++){
          acc[tr][0] = mfma128(af[tr][kq], b0, acc[tr][0]);
          acc[tr][1] = mfma128(af[tr][kq], b1, acc[tr][1]);
        }
      }
      #pragma unroll
      for(int tc2=0;tc2<2;tc2++){
        int tc = hf*2 + tc2;
        int vg = vbase + wj*64 + tc*16 + rr;
        bool vok = vg < vc1;
        float bo = vok ? b_out[vg] : 0.f;
        #pragma unroll
        for(int tr=0;tr<4;tr++)
          #pragma unroll
          for(int reg=0;reg<4;reg++){
            float sc = acc[tr][tc2][reg] + bo;
            float ex = __builtin_amdgcn_exp2f(sc * 1.4426950408889634f);
            if(vok) sacc[tr*4+reg] += ex;
          }
      }
    }
    __syncthreads();
  }
  #pragma unroll
  for(int i=0;i<16;i++){
    float v = sacc[i];
    v += __shfl_xor(v, 1, 64);
    v += __shfl_xor(v, 2, 64);
    v += __shfl_xor(v, 4, 64);
    v += __shfl_xor(v, 8, 64);
    sacc[i] = v;
  }
  if(rr == 0){
    #pragma unroll
    for(int tr=0;tr<4;tr++)
      #pragma unroll
      for(int reg=0;reg<4;reg++)
        sred[wj][wi*64 + tr*16 + q*4 + reg] = sacc[tr*4+reg];
  }
  __syncthreads();
  if(tid < 128){
    int row = rb*128 + tid;
    if(row < RTOT) partial_s[row*4 + chunk] = sred[0][tid] + sred[1][tid];
  }
}

// ---------------- K4b: picked[R] = score(R, y_R)
__global__ __launch_bounds__(256) void k_picked(const unsigned char* __restrict__ hs8,
    const unsigned char* __restrict__ WoutT, const float* __restrict__ b_out,
    const int* __restrict__ captions, float* __restrict__ picked){
  int tid = threadIdx.x;
  int w = tid>>6, lane = tid&63;
  int R = blockIdx.x*4 + w;
  int t = R >> 6, n = R & 63;
  int y = captions[n*TT + t + 1];
  const unsigned int* hp = (const unsigned int*)(hs8 + (size_t)R*HD + lane*8);
  const unsigned int* wp = (const unsigned int*)(WoutT + (size_t)y*HD + lane*8);
  unsigned int hv0 = hp[0], hv1 = hp[1], wv0 = wp[0], wv1 = wp[1];
  float d = dot4_fp8(hv0, wv0) + dot4_fp8(hv1, wv1);
  d += __shfl_xor(d, 1, 64);
  d += __shfl_xor(d, 2, 64);
  d += __shfl_xor(d, 4, 64);
  d += __shfl_xor(d, 8, 64);
  d += __shfl_xor(d, 16, 64);
  d += __shfl_xor(d, 32, 64);
  if(lane == 0) picked[R] = d + b_out[y];
}

// ---------------- K5: loss
__global__ __launch_bounds__(256) void k_loss(const float* __restrict__ partial_s,
    const float* __restrict__ picked, const int* __restrict__ captions,
    float* __restrict__ out){
  int tid = threadIdx.x;
  float a = 0.f;
  for(int R = tid; R < RTOT; R += 256){
    int t = R >> 6, n = R & 63;
    int y = captions[n*TT + t + 1];
    if(y != 0){
      float s = partial_s[R*4] + partial_s[R*4+1] + partial_s[R*4+2] + partial_s[R*4+3];
      a += __logf(s) - picked[R];
    }
  }
  a += __shfl_xor(a, 1, 64);
  a += __shfl_xor(a, 2, 64);
  a += __shfl_xor(a, 4, 64);
  a += __shfl_xor(a, 8, 64);
  a += __shfl_xor(a, 16, 64);
  a += __shfl_xor(a, 32, 64);
  __shared__ float red[4];
  int w = tid>>6, lane = tid&63;
  if(lane == 0) red[w] = a;
  __syncthreads();
  if(tid == 0) out[0] = (red[0]+red[1]+red[2]+red[3]) * (1.0f/64.0f);
}

extern "C" void kernel_launch(void* const* d_in, const int* in_sizes, int n_in,
                              void* d_out, int out_size, void* d_ws, size_t ws_size,
                              hipStream_t stream) {
  const float* feat    = (const float*)d_in[0];
  const float* W_proj  = (const float*)d_in[1];
  const float* b_proj  = (const float*)d_in[2];
  const float* W_embed = (const float*)d_in[3];
  const float* Wx      = (const float*)d_in[4];
  const float* Wh      = (const float*)d_in[5];
  const float* bvec    = (const float*)d_in[6];
  const float* W_out   = (const float*)d_in[7];
  const float* b_out   = (const float*)d_in[8];
  const int*   captions= (const int*)d_in[9];

  char* p = (char*)d_ws;
  unsigned short* WprojT = (unsigned short*)p;  p += 512*1280*2;
  unsigned short* WxT    = (unsigned short*)p;  p += 512*256*2;
  unsigned char*  Wh8S   = (unsigned char*)p;   p += 512*512;
  unsigned char*  WoutT  = (unsigned char*)p;   p += 10000*512;
  unsigned short* Wembb  = (unsigned short*)p;  p += 10000*256*2;
  unsigned short* featb  = (unsigned short*)p;  p += 64*1280*2;
  unsigned short* h0b    = (unsigned short*)p;  p += 64*512*2;
  unsigned short* xWk    = (unsigned short*)p;  p += TS*64*512*2;
  unsigned char*  hs8    = (unsigned char*)p;   p += RPAD*512;
  float* partial_s       = (float*)p;           p += RTOT*4*4;
  float* picked          = (float*)p;           p += RTOT*4;
  if((size_t)(p - (char*)d_ws) > ws_size) return;

  k_transpose_cvt<0><<<dim3(40,16), 256, 0, stream>>>(W_proj, (unsigned char*)WprojT, 1280, 512);
  k_transpose_cvt<0><<<dim3(8,16),  256, 0, stream>>>(Wx,     (unsigned char*)WxT,    256,  512);
  k_cvt_whS<<<1024, 256, 0, stream>>>(Wh, Wh8S);
  k_transpose_cvt<1><<<dim3(16,313),256, 0, stream>>>(W_out,  WoutT,                  512,  10000);
  k_cvt_bf16<<<320,   256, 0, stream>>>(feat,    featb, 64*1280);
  k_cvt_bf16<<<10000, 256, 0, stream>>>(W_embed, Wembb, 10000*256);

  k_h0<<<8, 256, 0, stream>>>(featb, WprojT, b_proj, h0b);
  k_xw<<<dim3(8, TS), 256, 0, stream>>>(Wembb, WxT, bvec, captions, xWk);
  k_rnn<<<4, 512, 0, stream>>>(h0b, Wh8S, xWk, hs8);
  k_scores<<<dim3(4, 128), 256, 0, stream>>>(hs8, WoutT, b_out, partial_s);
  k_picked<<<4080, 256, 0, stream>>>(hs8, WoutT, b_out, captions, picked);
  k_loss<<<1, 256, 0, stream>>>(partial_s, picked, captions, (float*)d_out);
}

// Round 8
// 853.704 us; speedup vs baseline: 1.3734x; 1.0031x over previous
//
#include <hip/hip_runtime.h>

// Problem dims
#define NS 64      // batch
#define TT 256     // caption length
#define TS 255     // RNN timesteps (T-1)
#define VV 10000   // vocab
#define DF 1280    // feature dim
#define WD 256     // word-embed dim
#define HD 512     // hidden dim
#define RTOT (TS*NS)   // 16320 output rows (r = t*64 + n)
#define RPAD 16384     // padded rows for hs

typedef __attribute__((ext_vector_type(4))) float f32x4;
typedef __attribute__((ext_vector_type(8))) short s16x8;
typedef __attribute__((ext_vector_type(4))) unsigned int u32x4;
typedef __attribute__((ext_vector_type(8))) int i32x8;

__device__ __forceinline__ unsigned short f2bf(float f){
  unsigned u; __builtin_memcpy(&u, &f, 4);
  u += 0x7FFFu + ((u >> 16) & 1u);            // RNE
  return (unsigned short)(u >> 16);
}
__device__ __forceinline__ float bf2f(unsigned short h){
  unsigned u = ((unsigned)h) << 16; float f; __builtin_memcpy(&f, &u, 4); return f;
}
__device__ __forceinline__ unsigned char f2fp8(float f){
  int p = __builtin_amdgcn_cvt_pk_fp8_f32(f, f, 0, false);  // OCP e4m3
  return (unsigned char)(p & 0xFF);
}
__device__ __forceinline__ float dot4_fp8(unsigned int a, unsigned int b){
  float d;
  d  = __builtin_amdgcn_cvt_f32_fp8(a, 0) * __builtin_amdgcn_cvt_f32_fp8(b, 0);
  d += __builtin_amdgcn_cvt_f32_fp8(a, 1) * __builtin_amdgcn_cvt_f32_fp8(b, 1);
  d += __builtin_amdgcn_cvt_f32_fp8(a, 2) * __builtin_amdgcn_cvt_f32_fp8(b, 2);
  d += __builtin_amdgcn_cvt_f32_fp8(a, 3) * __builtin_amdgcn_cvt_f32_fp8(b, 3);
  return d;
}
// MX-scaled MFMA, fp8 x fp8, unit scales -> exact fp8 GEMM at 2x rate (verified r6, absmax 0.0)
__device__ __forceinline__ f32x4 mfma128(i32x8 a, i32x8 b, f32x4 c){
  return __builtin_amdgcn_mfma_scale_f32_16x16x128_f8f6f4(a, b, c, 0, 0, 0, 127, 0, 127);
}

// ---------------- K0: transpose + convert weights (fp32 [R][C] -> [C][R] bf16/fp8)
template<int FP8>
__global__ __launch_bounds__(256) void k_transpose_cvt(const float* __restrict__ src,
    unsigned char* __restrict__ dst, int R, int C){
  __shared__ float tile[32][33];
  int r0 = blockIdx.x*32, c0 = blockIdx.y*32;
  int tr = threadIdx.x >> 5, tc = threadIdx.x & 31;
  #pragma unroll
  for(int p=0;p<4;p++){
    int r = r0 + tr + p*8, c = c0 + tc;
    tile[tr + p*8][tc] = (r < R && c < C) ? src[r*C + c] : 0.f;
  }
  __syncthreads();
  #pragma unroll
  for(int p=0;p<4;p++){
    int oc = c0 + tr + p*8;   // dst row (C dim)
    int orow = r0 + tc;       // dst col (R dim)
    if(oc < C && orow < R){
      float v = tile[tc][tr + p*8];
      if(FP8) dst[oc*R + orow] = f2fp8(v);
      else ((unsigned short*)dst)[oc*R + orow] = f2bf(v);
    }
  }
}

// ---------------- K0w: Wh fp32 [k][j] -> Wh8S wave-order K=128-frag fp8.
__global__ __launch_bounds__(256) void k_cvt_whS(const float* __restrict__ Wh,
    unsigned char* __restrict__ Wh8S){
  int i = blockIdx.x*256 + threadIdx.x;      // 1024 blocks -> 256K bytes
  int blk = i>>11;
  int w = blk>>4, ct = (blk>>2)&3, kq = blk&3;
  int lane = (i>>5)&63, ib = i&31;
  int q = lane>>4, rr = lane&15;
  int k = kq*128 + q*32 + ib;
  int j = w*64 + ct*16 + rr;
  Wh8S[i] = f2fp8(Wh[k*HD + j]);
}

// ---------------- K0c: elementwise fp32 -> bf16
__global__ __launch_bounds__(256) void k_cvt_bf16(const float* __restrict__ src,
    unsigned short* __restrict__ dst, int n){
  int i = blockIdx.x*256 + threadIdx.x;
  if(i < n) dst[i] = f2bf(src[i]);
}

// ---------------- K1: h0 = feat @ W_proj + b_proj  -> bf16 [64][512]
__global__ __launch_bounds__(256) void k_h0(const unsigned short* __restrict__ featb,
    const unsigned short* __restrict__ WprojT, const float* __restrict__ b_proj,
    unsigned short* __restrict__ h0b){
  __shared__ unsigned short Al[64*264];
  __shared__ unsigned short Bl[64*264];
  int tid = threadIdx.x, cb = blockIdx.x;
  int w = tid>>6, lane = tid&63, q = lane>>4, rr = lane&15;
  f32x4 acc[4];
  #pragma unroll
  for(int i=0;i<4;i++){ acc[i][0]=0.f; acc[i][1]=0.f; acc[i][2]=0.f; acc[i][3]=0.f; }
  for(int kb=0; kb<5; kb++){
    {
      int row = tid >> 2, part = tid & 3;
      const u32x4* s = (const u32x4*)(featb + row*DF + kb*256 + part*64);
      u32x4* d = (u32x4*)(Al + row*264 + part*64);
      #pragma unroll
      for(int i=0;i<8;i++) d[i] = s[i];
    }
    {
      int row = tid >> 2, part = tid & 3;
      int j = cb*64 + row;
      const u32x4* s = (const u32x4*)(WprojT + j*DF + kb*256 + part*64);
      u32x4* d = (u32x4*)(Bl + row*264 + part*64);
      #pragma unroll
      for(int i=0;i<8;i++) d[i] = s[i];
    }
    __syncthreads();
    #pragma unroll
    for(int kc=0;kc<8;kc++){
      s16x8 a = *(const s16x8*)(Al + (w*16 + rr)*264 + kc*32 + q*8);
      #pragma unroll
      for(int tc=0;tc<4;tc++){
        s16x8 bb = *(const s16x8*)(Bl + (tc*16 + rr)*264 + kc*32 + q*8);
        acc[tc] = __builtin_amdgcn_mfma_f32_16x16x32_bf16(a, bb, acc[tc], 0, 0, 0);
      }
    }
    __syncthreads();
  }
  #pragma unroll
  for(int tc=0;tc<4;tc++){
    #pragma unroll
    for(int reg=0;reg<4;reg++){
      int n = w*16 + q*4 + reg;
      int j = cb*64 + tc*16 + rr;
      h0b[n*HD + j] = f2bf(acc[tc][reg] + b_proj[j]);
    }
  }
}

// ---------------- K2: xW + b -> xWk in K3-thread-major layout.
__global__ __launch_bounds__(256) void k_xw(const unsigned short* __restrict__ Wembb,
    const unsigned short* __restrict__ WxT, const float* __restrict__ bvec,
    const int* __restrict__ captions, unsigned short* __restrict__ xWk){
  __shared__ unsigned short Al[64*264];
  __shared__ unsigned short Bl[64*264];
  int tid = threadIdx.x, cb = blockIdx.x, t = blockIdx.y;
  int w = tid>>6, lane = tid&63, q = lane>>4, rr = lane&15;
  {
    int row = tid >> 2, part = tid & 3;
    int idx = captions[row*TT + t];
    const u32x4* s = (const u32x4*)(Wembb + idx*WD + part*64);
    u32x4* d = (u32x4*)(Al + row*264 + part*64);
    #pragma unroll
    for(int i=0;i<8;i++) d[i] = s[i];
  }
  {
    int row = tid >> 2, part = tid & 3;
    int j = cb*64 + row;
    const u32x4* s = (const u32x4*)(WxT + j*WD + part*64);
    u32x4* d = (u32x4*)(Bl + row*264 + part*64);
    #pragma unroll
    for(int i=0;i<8;i++) d[i] = s[i];
  }
  __syncthreads();
  f32x4 acc[4];
  #pragma unroll
  for(int i=0;i<4;i++){ acc[i][0]=0.f; acc[i][1]=0.f; acc[i][2]=0.f; acc[i][3]=0.f; }
  #pragma unroll
  for(int kc=0;kc<8;kc++){
    s16x8 a = *(const s16x8*)(Al + (w*16 + rr)*264 + kc*32 + q*8);
    #pragma unroll
    for(int tc=0;tc<4;tc++){
      s16x8 bb = *(const s16x8*)(Bl + (tc*16 + rr)*264 + kc*32 + q*8);
      acc[tc] = __builtin_amdgcn_mfma_f32_16x16x32_bf16(a, bb, acc[tc], 0, 0, 0);
    }
  }
  #pragma unroll
  for(int tc=0;tc<4;tc++){
    int j = cb*64 + tc*16 + rr;
    float bo = bvec[j];
    unsigned short st[4];
    #pragma unroll
    for(int reg=0;reg<4;reg++)
      st[reg] = f2bf(acc[tc][reg] + bo);
    size_t f = (((size_t)t*4 + w)*8 + cb)*1024 + q*256 + rr*16 + tc*4;
    unsigned long v; __builtin_memcpy(&v, st, 8);
    *(unsigned long*)(xWk + f) = v;
  }
}

// ---------------- K3: RNN scan. ALL Wh B-frags resident in VGPRs (128/thread).
// amdgpu_waves_per_eu(2,2): clamp occupancy target -> 256-VGPR budget -> no remat.
__global__ __launch_bounds__(512, 2) __attribute__((amdgpu_waves_per_eu(2, 2)))
void k_rnn(const unsigned short* __restrict__ h0b,
    const unsigned char* __restrict__ Wh8S, const unsigned short* __restrict__ xWk,
    unsigned char* __restrict__ hs8){
  __shared__ unsigned char hbuf[2][16*560];    // fp8 h, stride 560
  int tid = threadIdx.x, w = tid>>6, lane = tid&63, q = lane>>4, rr = lane&15;
  int n0 = blockIdx.x * 16;
  int j0 = w * 64;
  i32x8 wb[16];
  #pragma unroll
  for(int ct=0;ct<4;ct++)
    #pragma unroll
    for(int kq=0;kq<4;kq++)
      wb[ct*4+kq] = *(const i32x8*)(Wh8S + (size_t)((w*4+ct)*4+kq)*2048 + lane*32);
  {
    int s = tid>>5, c0 = (tid&31)*16;
    #pragma unroll
    for(int i=0;i<16;i++)
      hbuf[0][s*560 + c0 + i] = f2fp8(bf2f(h0b[(n0+s)*HD + c0 + i]));
  }
  __syncthreads();
  int scp = tid>>5, scc = (tid&31)*16;
  const unsigned short* xp = xWk + (((size_t)blockIdx.x)*8 + w)*1024 + q*256 + rr*16;
  for(int t=0; t<TS; t++){
    const unsigned char* hb = hbuf[t&1];
    unsigned char*       hn = hbuf[(t&1)^1];
    if(t)
      *(u32x4*)(hs8 + (size_t)((t-1)*NS + n0 + scp)*HD + scc) = *(const u32x4*)(hb + scp*560 + scc);
    unsigned short xs[16];
    *(u32x4*)(xs)   = *(const u32x4*)(xp);
    *(u32x4*)(xs+8) = *(const u32x4*)(xp+8);
    i32x8 af[4];
    #pragma unroll
    for(int kq=0;kq<4;kq++)
      af[kq] = *(const i32x8*)(hb + rr*560 + kq*128 + q*32);
    f32x4 acc[4];
    #pragma unroll
    for(int ct=0;ct<4;ct++){ acc[ct][0]=0.f; acc[ct][1]=0.f; acc[ct][2]=0.f; acc[ct][3]=0.f; }
    #pragma unroll
    for(int ct=0;ct<4;ct++)
      #pragma unroll
      for(int kq=0;kq<4;kq++)
        acc[ct] = mfma128(af[kq], wb[ct*4+kq], acc[ct]);
    #pragma unroll
    for(int ct=0;ct<4;ct++){
      int j = j0 + ct*16 + rr;
      #pragma unroll
      for(int reg=0;reg<4;reg++){
        int nl = q*4 + reg;
        float pre = acc[ct][reg] + bf2f(xs[ct*4+reg]);
        float e2 = __builtin_amdgcn_exp2f(pre * 2.8853900817779268f); // e^(2x)
        float h = (e2 - 1.f) * __builtin_amdgcn_rcpf(e2 + 1.f);       // tanh
        hn[nl*560 + j] = f2fp8(h);
      }
    }
    __syncthreads();
    xp += 32768;
  }
  *(u32x4*)(hs8 + (size_t)((TS-1)*NS + n0 + scp)*HD + scc) = *(const u32x4*)(hbuf[TS&1] + scp*560 + scc);
}

// ---------------- K4: fused scores GEMM (MX-fp8 K=128) + sumexp partials.
// amdgpu_waves_per_eu(2,2): af[4][4] (128 VGPR) stays register-resident.
__global__ __launch_bounds__(256, 2) __attribute__((amdgpu_waves_per_eu(2, 2)))
void k_scores(const unsigned char* __restrict__ hs8,
    const unsigned char* __restrict__ WoutT, const float* __restrict__ b_out,
    float* __restrict__ partial_s){
  __shared__ unsigned char Bl[128*528];
  __shared__ float sred[2][128];
  int tid = threadIdx.x;
  int chunk = blockIdx.x, rb = blockIdx.y;
  int w = tid>>6, lane = tid&63, q = lane>>4, rr = lane&15;
  int wi = w>>1, wj = w&1;
  i32x8 af[4][4];
  #pragma unroll
  for(int tr=0;tr<4;tr++)
    #pragma unroll
    for(int kq=0;kq<4;kq++){
      int row = rb*128 + wi*64 + tr*16 + rr;
      af[tr][kq] = *(const i32x8*)(hs8 + (size_t)row*HD + kq*128 + q*32);
    }
  float sacc[16];
  #pragma unroll
  for(int i=0;i<16;i++) sacc[i]=0.f;
  int vc0 = chunk*2500, vc1 = vc0 + 2500;
  for(int vt=0; vt<20; vt++){
    int vbase = vc0 + vt*128;
    {
      int v = tid>>1, half = tid&1;
      int vg = vbase + v; if(vg > VV-1) vg = VV-1;
      const u32x4* s = (const u32x4*)(WoutT + (size_t)vg*HD + half*256);
      u32x4* d = (u32x4*)(Bl + v*528 + half*256);
      #pragma unroll
      for(int i=0;i<16;i++) d[i] = s[i];
    }
    __syncthreads();
    #pragma unroll
    for(int hf=0; hf<2; hf++){
      f32x4 acc[4][2];
      #pragma unroll
      for(int a=0;a<4;a++)
        #pragma unroll
        for(int b=0;b<2;b++){ acc[a][b][0]=0.f; acc[a][b][1]=0.f; acc[a][b][2]=0.f; acc[a][b][3]=0.f; }
      #pragma unroll
      for(int kq=0;kq<4;kq++){
        i32x8 b0 = *(const i32x8*)(Bl + (wj*64 + (hf*2  )*16 + rr)*528 + kq*128 + q*32);
        i32x8 b1 = *(const i32x8*)(Bl + (wj*64 + (hf*2+1)*16 + rr)*528 + kq*128 + q*32);
        #pragma unroll
        for(int tr=0;tr<4;tr++){
          acc[tr][0] = mfma128(af[tr][kq], b0, acc[tr][0]);
          acc[tr][1] = mfma128(af[tr][kq], b1, acc[tr][1]);
        }
      }
      #pragma unroll
      for(int tc2=0;tc2<2;tc2++){
        int tc = hf*2 + tc2;
        int vg = vbase + wj*64 + tc*16 + rr;
        bool vok = vg < vc1;
        float bo = vok ? b_out[vg] : 0.f;
        #pragma unroll
        for(int tr=0;tr<4;tr++)
          #pragma unroll
          for(int reg=0;reg<4;reg++){
            float sc = acc[tr][tc2][reg] + bo;
            float ex = __builtin_amdgcn_exp2f(sc * 1.4426950408889634f);
            if(vok) sacc[tr*4+reg] += ex;
          }
      }
    }
    __syncthreads();
  }
  #pragma unroll
  for(int i=0;i<16;i++){
    float v = sacc[i];
    v += __shfl_xor(v, 1, 64);
    v += __shfl_xor(v, 2, 64);
    v += __shfl_xor(v, 4, 64);
    v += __shfl_xor(v, 8, 64);
    sacc[i] = v;
  }
  if(rr == 0){
    #pragma unroll
    for(int tr=0;tr<4;tr++)
      #pragma unroll
      for(int reg=0;reg<4;reg++)
        sred[wj][wi*64 + tr*16 + q*4 + reg] = sacc[tr*4+reg];
  }
  __syncthreads();
  if(tid < 128){
    int row = rb*128 + tid;
    if(row < RTOT) partial_s[row*4 + chunk] = sred[0][tid] + sred[1][tid];
  }
}

// ---------------- K4b: picked[R] = score(R, y_R)
__global__ __launch_bounds__(256) void k_picked(const unsigned char* __restrict__ hs8,
    const unsigned char* __restrict__ WoutT, const float* __restrict__ b_out,
    const int* __restrict__ captions, float* __restrict__ picked){
  int tid = threadIdx.x;
  int w = tid>>6, lane = tid&63;
  int R = blockIdx.x*4 + w;
  int t = R >> 6, n = R & 63;
  int y = captions[n*TT + t + 1];
  const unsigned int* hp = (const unsigned int*)(hs8 + (size_t)R*HD + lane*8);
  const unsigned int* wp = (const unsigned int*)(WoutT + (size_t)y*HD + lane*8);
  unsigned int hv0 = hp[0], hv1 = hp[1], wv0 = wp[0], wv1 = wp[1];
  float d = dot4_fp8(hv0, wv0) + dot4_fp8(hv1, wv1);
  d += __shfl_xor(d, 1, 64);
  d += __shfl_xor(d, 2, 64);
  d += __shfl_xor(d, 4, 64);
  d += __shfl_xor(d, 8, 64);
  d += __shfl_xor(d, 16, 64);
  d += __shfl_xor(d, 32, 64);
  if(lane == 0) picked[R] = d + b_out[y];
}

// ---------------- K5: loss
__global__ __launch_bounds__(256) void k_loss(const float* __restrict__ partial_s,
    const float* __restrict__ picked, const int* __restrict__ captions,
    float* __restrict__ out){
  int tid = threadIdx.x;
  float a = 0.f;
  for(int R = tid; R < RTOT; R += 256){
    int t = R >> 6, n = R & 63;
    int y = captions[n*TT + t + 1];
    if(y != 0){
      float s = partial_s[R*4] + partial_s[R*4+1] + partial_s[R*4+2] + partial_s[R*4+3];
      a += __logf(s) - picked[R];
    }
  }
  a += __shfl_xor(a, 1, 64);
  a += __shfl_xor(a, 2, 64);
  a += __shfl_xor(a, 4, 64);
  a += __shfl_xor(a, 8, 64);
  a += __shfl_xor(a, 16, 64);
  a += __shfl_xor(a, 32, 64);
  __shared__ float red[4];
  int w = tid>>6, lane = tid&63;
  if(lane == 0) red[w] = a;
  __syncthreads();
  if(tid == 0) out[0] = (red[0]+red[1]+red[2]+red[3]) * (1.0f/64.0f);
}

extern "C" void kernel_launch(void* const* d_in, const int* in_sizes, int n_in,
                              void* d_out, int out_size, void* d_ws, size_t ws_size,
                              hipStream_t stream) {
  const float* feat    = (const float*)d_in[0];
  const float* W_proj  = (const float*)d_in[1];
  const float* b_proj  = (const float*)d_in[2];
  const float* W_embed = (const float*)d_in[3];
  const float* Wx      = (const float*)d_in[4];
  const float* Wh      = (const float*)d_in[5];
  const float* bvec    = (const float*)d_in[6];
  const float* W_out   = (const float*)d_in[7];
  const float* b_out   = (const float*)d_in[8];
  const int*   captions= (const int*)d_in[9];

  char* p = (char*)d_ws;
  unsigned short* WprojT = (unsigned short*)p;  p += 512*1280*2;
  unsigned short* WxT    = (unsigned short*)p;  p += 512*256*2;
  unsigned char*  Wh8S   = (unsigned char*)p;   p += 512*512;
  unsigned char*  WoutT  = (unsigned char*)p;   p += 10000*512;
  unsigned short* Wembb  = (unsigned short*)p;  p += 10000*256*2;
  unsigned short* featb  = (unsigned short*)p;  p += 64*1280*2;
  unsigned short* h0b    = (unsigned short*)p;  p += 64*512*2;
  unsigned short* xWk    = (unsigned short*)p;  p += TS*64*512*2;
  unsigned char*  hs8    = (unsigned char*)p;   p += RPAD*512;
  float* partial_s       = (float*)p;           p += RTOT*4*4;
  float* picked          = (float*)p;           p += RTOT*4;
  if((size_t)(p - (char*)d_ws) > ws_size) return;

  k_transpose_cvt<0><<<dim3(40,16), 256, 0, stream>>>(W_proj, (unsigned char*)WprojT, 1280, 512);
  k_transpose_cvt<0><<<dim3(8,16),  256, 0, stream>>>(Wx,     (unsigned char*)WxT,    256,  512);
  k_cvt_whS<<<1024, 256, 0, stream>>>(Wh, Wh8S);
  k_transpose_cvt<1><<<dim3(16,313),256, 0, stream>>>(W_out,  WoutT,                  512,  10000);
  k_cvt_bf16<<<320,   256, 0, stream>>>(feat,    featb, 64*1280);
  k_cvt_bf16<<<10000, 256, 0, stream>>>(W_embed, Wembb, 10000*256);

  k_h0<<<8, 256, 0, stream>>>(featb, WprojT, b_proj, h0b);
  k_xw<<<dim3(8, TS), 256, 0, stream>>>(Wembb, WxT, bvec, captions, xWk);
  k_rnn<<<4, 512, 0, stream>>>(h0b, Wh8S, xWk, hs8);
  k_scores<<<dim3(4, 128), 256, 0, stream>>>(hs8, WoutT, b_out, partial_s);
  k_picked<<<4080, 256, 0, stream>>>(hs8, WoutT, b_out, captions, picked);
  k_loss<<<1, 256, 0, stream>>>(partial_s, picked, captions, (float*)d_out);
}

// Round 9
// 804.717 us; speedup vs baseline: 1.4570x; 1.0609x over previous
//
#include <hip/hip_runtime.h>

// Problem dims
#define NS 64      // batch
#define TT 256     // caption length
#define TS 255     // RNN timesteps (T-1)
#define VV 10000   // vocab
#define DF 1280    // feature dim
#define WD 256     // word-embed dim
#define HD 512     // hidden dim
#define RTOT (TS*NS)   // 16320 output rows (r = t*64 + n)
#define RPAD 16384     // padded rows for hs

typedef __attribute__((ext_vector_type(4))) float f32x4;
typedef __attribute__((ext_vector_type(8))) short s16x8;
typedef __attribute__((ext_vector_type(4))) unsigned int u32x4;
typedef __attribute__((ext_vector_type(8))) int i32x8;

__device__ __forceinline__ unsigned short f2bf(float f){
  unsigned u; __builtin_memcpy(&u, &f, 4);
  u += 0x7FFFu + ((u >> 16) & 1u);            // RNE
  return (unsigned short)(u >> 16);
}
__device__ __forceinline__ float bf2f(unsigned short h){
  unsigned u = ((unsigned)h) << 16; float f; __builtin_memcpy(&f, &u, 4); return f;
}
__device__ __forceinline__ unsigned char f2fp8(float f){
  int p = __builtin_amdgcn_cvt_pk_fp8_f32(f, f, 0, false);  // OCP e4m3
  return (unsigned char)(p & 0xFF);
}
__device__ __forceinline__ float dot4_fp8(unsigned int a, unsigned int b){
  float d;
  d  = __builtin_amdgcn_cvt_f32_fp8(a, 0) * __builtin_amdgcn_cvt_f32_fp8(b, 0);
  d += __builtin_amdgcn_cvt_f32_fp8(a, 1) * __builtin_amdgcn_cvt_f32_fp8(b, 1);
  d += __builtin_amdgcn_cvt_f32_fp8(a, 2) * __builtin_amdgcn_cvt_f32_fp8(b, 2);
  d += __builtin_amdgcn_cvt_f32_fp8(a, 3) * __builtin_amdgcn_cvt_f32_fp8(b, 3);
  return d;
}
// MX-scaled MFMA, fp8 x fp8, unit scales -> exact fp8 GEMM at 2x rate (verified r6-r8, absmax 0.0)
__device__ __forceinline__ f32x4 mfma128(i32x8 a, i32x8 b, f32x4 c){
  return __builtin_amdgcn_mfma_scale_f32_16x16x128_f8f6f4(a, b, c, 0, 0, 0, 127, 0, 127);
}

// ---------------- K0: transpose + convert weights (fp32 [R][C] -> [C][R] bf16/fp8)
template<int FP8>
__global__ __launch_bounds__(256) void k_transpose_cvt(const float* __restrict__ src,
    unsigned char* __restrict__ dst, int R, int C){
  __shared__ float tile[32][33];
  int r0 = blockIdx.x*32, c0 = blockIdx.y*32;
  int tr = threadIdx.x >> 5, tc = threadIdx.x & 31;
  #pragma unroll
  for(int p=0;p<4;p++){
    int r = r0 + tr + p*8, c = c0 + tc;
    tile[tr + p*8][tc] = (r < R && c < C) ? src[r*C + c] : 0.f;
  }
  __syncthreads();
  #pragma unroll
  for(int p=0;p<4;p++){
    int oc = c0 + tr + p*8;   // dst row (C dim)
    int orow = r0 + tc;       // dst col (R dim)
    if(oc < C && orow < R){
      float v = tile[tc][tr + p*8];
      if(FP8) dst[oc*R + orow] = f2fp8(v);
      else ((unsigned short*)dst)[oc*R + orow] = f2bf(v);
    }
  }
}

// ---------------- K0w: Wh fp32 [k][j] -> Wh8S wave-order K=128-frag fp8.
__global__ __launch_bounds__(256) void k_cvt_whS(const float* __restrict__ Wh,
    unsigned char* __restrict__ Wh8S){
  int i = blockIdx.x*256 + threadIdx.x;      // 1024 blocks -> 256K bytes
  int blk = i>>11;
  int w = blk>>4, ct = (blk>>2)&3, kq = blk&3;
  int lane = (i>>5)&63, ib = i&31;
  int q = lane>>4, rr = lane&15;
  int k = kq*128 + q*32 + ib;
  int j = w*64 + ct*16 + rr;
  Wh8S[i] = f2fp8(Wh[k*HD + j]);
}

// ---------------- K0c: elementwise fp32 -> bf16
__global__ __launch_bounds__(256) void k_cvt_bf16(const float* __restrict__ src,
    unsigned short* __restrict__ dst, int n){
  int i = blockIdx.x*256 + threadIdx.x;
  if(i < n) dst[i] = f2bf(src[i]);
}

// ---------------- K1: h0 = feat @ W_proj + b_proj  -> bf16 [64][512]
__global__ __launch_bounds__(256) void k_h0(const unsigned short* __restrict__ featb,
    const unsigned short* __restrict__ WprojT, const float* __restrict__ b_proj,
    unsigned short* __restrict__ h0b){
  __shared__ unsigned short Al[64*264];
  __shared__ unsigned short Bl[64*264];
  int tid = threadIdx.x, cb = blockIdx.x;
  int w = tid>>6, lane = tid&63, q = lane>>4, rr = lane&15;
  f32x4 acc[4];
  #pragma unroll
  for(int i=0;i<4;i++){ acc[i][0]=0.f; acc[i][1]=0.f; acc[i][2]=0.f; acc[i][3]=0.f; }
  for(int kb=0; kb<5; kb++){
    {
      int row = tid >> 2, part = tid & 3;
      const u32x4* s = (const u32x4*)(featb + row*DF + kb*256 + part*64);
      u32x4* d = (u32x4*)(Al + row*264 + part*64);
      #pragma unroll
      for(int i=0;i<8;i++) d[i] = s[i];
    }
    {
      int row = tid >> 2, part = tid & 3;
      int j = cb*64 + row;
      const u32x4* s = (const u32x4*)(WprojT + j*DF + kb*256 + part*64);
      u32x4* d = (u32x4*)(Bl + row*264 + part*64);
      #pragma unroll
      for(int i=0;i<8;i++) d[i] = s[i];
    }
    __syncthreads();
    #pragma unroll
    for(int kc=0;kc<8;kc++){
      s16x8 a = *(const s16x8*)(Al + (w*16 + rr)*264 + kc*32 + q*8);
      #pragma unroll
      for(int tc=0;tc<4;tc++){
        s16x8 bb = *(const s16x8*)(Bl + (tc*16 + rr)*264 + kc*32 + q*8);
        acc[tc] = __builtin_amdgcn_mfma_f32_16x16x32_bf16(a, bb, acc[tc], 0, 0, 0);
      }
    }
    __syncthreads();
  }
  #pragma unroll
  for(int tc=0;tc<4;tc++){
    #pragma unroll
    for(int reg=0;reg<4;reg++){
      int n = w*16 + q*4 + reg;
      int j = cb*64 + tc*16 + rr;
      h0b[n*HD + j] = f2bf(acc[tc][reg] + b_proj[j]);
    }
  }
}

// ---------------- K2: xW + b -> xWk in K3-thread-major layout.
__global__ __launch_bounds__(256) void k_xw(const unsigned short* __restrict__ Wembb,
    const unsigned short* __restrict__ WxT, const float* __restrict__ bvec,
    const int* __restrict__ captions, unsigned short* __restrict__ xWk){
  __shared__ unsigned short Al[64*264];
  __shared__ unsigned short Bl[64*264];
  int tid = threadIdx.x, cb = blockIdx.x, t = blockIdx.y;
  int w = tid>>6, lane = tid&63, q = lane>>4, rr = lane&15;
  {
    int row = tid >> 2, part = tid & 3;
    int idx = captions[row*TT + t];
    const u32x4* s = (const u32x4*)(Wembb + idx*WD + part*64);
    u32x4* d = (u32x4*)(Al + row*264 + part*64);
    #pragma unroll
    for(int i=0;i<8;i++) d[i] = s[i];
  }
  {
    int row = tid >> 2, part = tid & 3;
    int j = cb*64 + row;
    const u32x4* s = (const u32x4*)(WxT + j*WD + part*64);
    u32x4* d = (u32x4*)(Bl + row*264 + part*64);
    #pragma unroll
    for(int i=0;i<8;i++) d[i] = s[i];
  }
  __syncthreads();
  f32x4 acc[4];
  #pragma unroll
  for(int i=0;i<4;i++){ acc[i][0]=0.f; acc[i][1]=0.f; acc[i][2]=0.f; acc[i][3]=0.f; }
  #pragma unroll
  for(int kc=0;kc<8;kc++){
    s16x8 a = *(const s16x8*)(Al + (w*16 + rr)*264 + kc*32 + q*8);
    #pragma unroll
    for(int tc=0;tc<4;tc++){
      s16x8 bb = *(const s16x8*)(Bl + (tc*16 + rr)*264 + kc*32 + q*8);
      acc[tc] = __builtin_amdgcn_mfma_f32_16x16x32_bf16(a, bb, acc[tc], 0, 0, 0);
    }
  }
  #pragma unroll
  for(int tc=0;tc<4;tc++){
    int j = cb*64 + tc*16 + rr;
    float bo = bvec[j];
    unsigned short st[4];
    #pragma unroll
    for(int reg=0;reg<4;reg++)
      st[reg] = f2bf(acc[tc][reg] + bo);
    size_t f = (((size_t)t*4 + w)*8 + cb)*1024 + q*256 + rr*16 + tc*4;
    unsigned long v; __builtin_memcpy(&v, st, 8);
    *(unsigned long*)(xWk + f) = v;
  }
}

// ---------------- K3: RNN scan, K=128 MX MFMA. Wh residency 3-way within the
// compiler's 128-VGPR budget: ct{0,1} in LDS (128KB, loaded once), ct{2,3}
// streamed L2->VGPR (128KB/step/CU, fully-coalesced 2KB wave blocks).
__global__ __launch_bounds__(512, 2) void k_rnn(const unsigned short* __restrict__ h0b,
    const unsigned char* __restrict__ Wh8S, const unsigned short* __restrict__ xWk,
    unsigned char* __restrict__ hs8){
  __shared__ unsigned char whl[131072];        // ct=0,1 slabs, wave-frag order
  __shared__ unsigned char hbuf[2][16*560];    // fp8 h, stride 560
  int tid = threadIdx.x, w = tid>>6, lane = tid&63, q = lane>>4, rr = lane&15;
  int n0 = blockIdx.x * 16;
  int j0 = w * 64;
  // preload LDS half of Wh: LDS block l=(w*2+ct)*4+kq <- global block (w*4+ct)*4+kq
  #pragma unroll
  for(int i=0;i<16;i++){
    int o = (i*512 + tid)*16;
    int l = o >> 11;
    int gblk = ((l>>3)*4 + ((l>>2)&1))*4 + (l&3);
    *(u32x4*)(whl + o) = *(const u32x4*)(Wh8S + gblk*2048 + (o & 2047));
  }
  {
    int s = tid>>5, c0 = (tid&31)*16;
    #pragma unroll
    for(int i=0;i<16;i++)
      hbuf[0][s*560 + c0 + i] = f2fp8(bf2f(h0b[(n0+s)*HD + c0 + i]));
  }
  __syncthreads();
  int scp = tid>>5, scc = (tid&31)*16;
  const unsigned short* xp = xWk + (((size_t)blockIdx.x)*8 + w)*1024 + q*256 + rr*16;
  for(int t=0; t<TS; t++){
    const unsigned char* hb = hbuf[t&1];
    unsigned char*       hn = hbuf[(t&1)^1];
    // issue streamed B loads first (ct=2,3): 2KB/wave per block, coalesced
    i32x8 ws2[4], ws3[4];
    #pragma unroll
    for(int kq=0;kq<4;kq++)
      ws2[kq] = *(const i32x8*)(Wh8S + (size_t)((w*4+2)*4+kq)*2048 + lane*32);
    #pragma unroll
    for(int kq=0;kq<4;kq++)
      ws3[kq] = *(const i32x8*)(Wh8S + (size_t)((w*4+3)*4+kq)*2048 + lane*32);
    if(t)
      *(u32x4*)(hs8 + (size_t)((t-1)*NS + n0 + scp)*HD + scc) = *(const u32x4*)(hb + scp*560 + scc);
    unsigned short xs[16];
    *(u32x4*)(xs)   = *(const u32x4*)(xp);
    *(u32x4*)(xs+8) = *(const u32x4*)(xp+8);
    i32x8 af[4];
    #pragma unroll
    for(int kq=0;kq<4;kq++)
      af[kq] = *(const i32x8*)(hb + rr*560 + kq*128 + q*32);
    f32x4 acc[4];
    #pragma unroll
    for(int ct=0;ct<4;ct++){ acc[ct][0]=0.f; acc[ct][1]=0.f; acc[ct][2]=0.f; acc[ct][3]=0.f; }
    // LDS-resident cts (0,1) first — streamed loads drain meanwhile
    #pragma unroll
    for(int ct=0;ct<2;ct++)
      #pragma unroll
      for(int kq=0;kq<4;kq++){
        i32x8 bv = *(const i32x8*)(whl + (size_t)((w*2+ct)*4+kq)*2048 + lane*32);
        acc[ct] = mfma128(af[kq], bv, acc[ct]);
      }
    #pragma unroll
    for(int kq=0;kq<4;kq++) acc[2] = mfma128(af[kq], ws2[kq], acc[2]);
    #pragma unroll
    for(int kq=0;kq<4;kq++) acc[3] = mfma128(af[kq], ws3[kq], acc[3]);
    #pragma unroll
    for(int ct=0;ct<4;ct++){
      int j = j0 + ct*16 + rr;
      #pragma unroll
      for(int reg=0;reg<4;reg++){
        int nl = q*4 + reg;
        float pre = acc[ct][reg] + bf2f(xs[ct*4+reg]);
        float e2 = __builtin_amdgcn_exp2f(pre * 2.8853900817779268f); // e^(2x)
        float h = (e2 - 1.f) * __builtin_amdgcn_rcpf(e2 + 1.f);       // tanh
        hn[nl*560 + j] = f2fp8(h);
      }
    }
    __syncthreads();
    xp += 32768;
  }
  *(u32x4*)(hs8 + (size_t)((TS-1)*NS + n0 + scp)*HD + scc) = *(const u32x4*)(hbuf[TS&1] + scp*560 + scc);
}

// ---------------- K4: fused scores GEMM + sumexp partials.
// Round-1 proven structure: fp8 K=32, long af[4][16] (allocator keeps 2-reg pairs
// resident at launch_bounds(256,2)), 128-row tiles. Measured 132.6 us in round 1.
__global__ __launch_bounds__(256, 2) void k_scores(const unsigned char* __restrict__ hs8,
    const unsigned char* __restrict__ WoutT, const float* __restrict__ b_out,
    float* __restrict__ partial_s){
  __shared__ unsigned char Bl[128*528];
  __shared__ float sred[2][128];
  int tid = threadIdx.x;
  int chunk = blockIdx.x, rb = blockIdx.y;
  int w = tid>>6, lane = tid&63, q = lane>>4, rr = lane&15;
  int wi = w>>1, wj = w&1;
  long af[4][16];
  #pragma unroll
  for(int tr=0;tr<4;tr++)
    #pragma unroll
    for(int kc=0;kc<16;kc++){
      int row = rb*128 + wi*64 + tr*16 + rr;   // < RPAD always
      af[tr][kc] = *(const long*)(hs8 + (size_t)row*HD + kc*32 + q*8);
    }
  float sacc[16];
  #pragma unroll
  for(int i=0;i<16;i++) sacc[i]=0.f;
  int vc0 = chunk*2500, vc1 = vc0 + 2500;
  for(int vt=0; vt<20; vt++){
    int vbase = vc0 + vt*128;
    {
      int v = tid>>1, half = tid&1;
      int vg = vbase + v; if(vg > VV-1) vg = VV-1;
      const u32x4* s = (const u32x4*)(WoutT + (size_t)vg*HD + half*256);
      u32x4* d = (u32x4*)(Bl + v*528 + half*256);
      #pragma unroll
      for(int i=0;i<16;i++) d[i] = s[i];
    }
    __syncthreads();
    f32x4 acc[4][4];
    #pragma unroll
    for(int a=0;a<4;a++)
      #pragma unroll
      for(int b=0;b<4;b++){ acc[a][b][0]=0.f; acc[a][b][1]=0.f; acc[a][b][2]=0.f; acc[a][b][3]=0.f; }
    #pragma unroll
    for(int kc=0;kc<16;kc++){
      long bf[4];
      #pragma unroll
      for(int tc=0;tc<4;tc++)
        bf[tc] = *(const long*)(Bl + (wj*64 + tc*16 + rr)*528 + kc*32 + q*8);
      #pragma unroll
      for(int tr=0;tr<4;tr++)
        #pragma unroll
        for(int tc=0;tc<4;tc++)
          acc[tr][tc] = __builtin_amdgcn_mfma_f32_16x16x32_fp8_fp8(af[tr][kc], bf[tc], acc[tr][tc], 0, 0, 0);
    }
    #pragma unroll
    for(int tc=0;tc<4;tc++){
      int vg = vbase + wj*64 + tc*16 + rr;
      bool vok = vg < vc1;
      float bo = vok ? b_out[vg] : 0.f;
      #pragma unroll
      for(int tr=0;tr<4;tr++)
        #pragma unroll
        for(int reg=0;reg<4;reg++){
          float sc = acc[tr][tc][reg] + bo;
          float ex = __builtin_amdgcn_exp2f(sc * 1.4426950408889634f);
          if(vok) sacc[tr*4+reg] += ex;
        }
    }
    __syncthreads();
  }
  #pragma unroll
  for(int i=0;i<16;i++){
    float v = sacc[i];
    v += __shfl_xor(v, 1, 64);
    v += __shfl_xor(v, 2, 64);
    v += __shfl_xor(v, 4, 64);
    v += __shfl_xor(v, 8, 64);
    sacc[i] = v;
  }
  if(rr == 0){
    #pragma unroll
    for(int tr=0;tr<4;tr++)
      #pragma unroll
      for(int reg=0;reg<4;reg++)
        sred[wj][wi*64 + tr*16 + q*4 + reg] = sacc[tr*4+reg];
  }
  __syncthreads();
  if(tid < 128){
    int row = rb*128 + tid;
    if(row < RTOT) partial_s[row*4 + chunk] = sred[0][tid] + sred[1][tid];
  }
}

// ---------------- K4b: picked[R] = score(R, y_R)
__global__ __launch_bounds__(256) void k_picked(const unsigned char* __restrict__ hs8,
    const unsigned char* __restrict__ WoutT, const float* __restrict__ b_out,
    const int* __restrict__ captions, float* __restrict__ picked){
  int tid = threadIdx.x;
  int w = tid>>6, lane = tid&63;
  int R = blockIdx.x*4 + w;
  int t = R >> 6, n = R & 63;
  int y = captions[n*TT + t + 1];
  const unsigned int* hp = (const unsigned int*)(hs8 + (size_t)R*HD + lane*8);
  const unsigned int* wp = (const unsigned int*)(WoutT + (size_t)y*HD + lane*8);
  unsigned int hv0 = hp[0], hv1 = hp[1], wv0 = wp[0], wv1 = wp[1];
  float d = dot4_fp8(hv0, wv0) + dot4_fp8(hv1, wv1);
  d += __shfl_xor(d, 1, 64);
  d += __shfl_xor(d, 2, 64);
  d += __shfl_xor(d, 4, 64);
  d += __shfl_xor(d, 8, 64);
  d += __shfl_xor(d, 16, 64);
  d += __shfl_xor(d, 32, 64);
  if(lane == 0) picked[R] = d + b_out[y];
}

// ---------------- K5: loss
__global__ __launch_bounds__(256) void k_loss(const float* __restrict__ partial_s,
    const float* __restrict__ picked, const int* __restrict__ captions,
    float* __restrict__ out){
  int tid = threadIdx.x;
  float a = 0.f;
  for(int R = tid; R < RTOT; R += 256){
    int t = R >> 6, n = R & 63;
    int y = captions[n*TT + t + 1];
    if(y != 0){
      float s = partial_s[R*4] + partial_s[R*4+1] + partial_s[R*4+2] + partial_s[R*4+3];
      a += __logf(s) - picked[R];
    }
  }
  a += __shfl_xor(a, 1, 64);
  a += __shfl_xor(a, 2, 64);
  a += __shfl_xor(a, 4, 64);
  a += __shfl_xor(a, 8, 64);
  a += __shfl_xor(a, 16, 64);
  a += __shfl_xor(a, 32, 64);
  __shared__ float red[4];
  int w = tid>>6, lane = tid&63;
  if(lane == 0) red[w] = a;
  __syncthreads();
  if(tid == 0) out[0] = (red[0]+red[1]+red[2]+red[3]) * (1.0f/64.0f);
}

extern "C" void kernel_launch(void* const* d_in, const int* in_sizes, int n_in,
                              void* d_out, int out_size, void* d_ws, size_t ws_size,
                              hipStream_t stream) {
  const float* feat    = (const float*)d_in[0];
  const float* W_proj  = (const float*)d_in[1];
  const float* b_proj  = (const float*)d_in[2];
  const float* W_embed = (const float*)d_in[3];
  const float* Wx      = (const float*)d_in[4];
  const float* Wh      = (const float*)d_in[5];
  const float* bvec    = (const float*)d_in[6];
  const float* W_out   = (const float*)d_in[7];
  const float* b_out   = (const float*)d_in[8];
  const int*   captions= (const int*)d_in[9];

  char* p = (char*)d_ws;
  unsigned short* WprojT = (unsigned short*)p;  p += 512*1280*2;
  unsigned short* WxT    = (unsigned short*)p;  p += 512*256*2;
  unsigned char*  Wh8S   = (unsigned char*)p;   p += 512*512;
  unsigned char*  WoutT  = (unsigned char*)p;   p += 10000*512;
  unsigned short* Wembb  = (unsigned short*)p;  p += 10000*256*2;
  unsigned short* featb  = (unsigned short*)p;  p += 64*1280*2;
  unsigned short* h0b    = (unsigned short*)p;  p += 64*512*2;
  unsigned short* xWk    = (unsigned short*)p;  p += TS*64*512*2;
  unsigned char*  hs8    = (unsigned char*)p;   p += RPAD*512;
  float* partial_s       = (float*)p;           p += RTOT*4*4;
  float* picked          = (float*)p;           p += RTOT*4;
  if((size_t)(p - (char*)d_ws) > ws_size) return;

  k_transpose_cvt<0><<<dim3(40,16), 256, 0, stream>>>(W_proj, (unsigned char*)WprojT, 1280, 512);
  k_transpose_cvt<0><<<dim3(8,16),  256, 0, stream>>>(Wx,     (unsigned char*)WxT,    256,  512);
  k_cvt_whS<<<1024, 256, 0, stream>>>(Wh, Wh8S);
  k_transpose_cvt<1><<<dim3(16,313),256, 0, stream>>>(W_out,  WoutT,                  512,  10000);
  k_cvt_bf16<<<320,   256, 0, stream>>>(feat,    featb, 64*1280);
  k_cvt_bf16<<<10000, 256, 0, stream>>>(W_embed, Wembb, 10000*256);

  k_h0<<<8, 256, 0, stream>>>(featb, WprojT, b_proj, h0b);
  k_xw<<<dim3(8, TS), 256, 0, stream>>>(Wembb, WxT, bvec, captions, xWk);
  k_rnn<<<4, 512, 0, stream>>>(h0b, Wh8S, xWk, hs8);
  k_scores<<<dim3(4, 128), 256, 0, stream>>>(hs8, WoutT, b_out, partial_s);
  k_picked<<<4080, 256, 0, stream>>>(hs8, WoutT, b_out, captions, picked);
  k_loss<<<1, 256, 0, stream>>>(partial_s, picked, captions, (float*)d_out);
}

// Round 10
// 730.155 us; speedup vs baseline: 1.6058x; 1.1021x over previous
//
#include <hip/hip_runtime.h>

// Problem dims
#define NS 64      // batch
#define TT 256     // caption length
#define TS 255     // RNN timesteps (T-1)
#define VV 10000   // vocab
#define DF 1280    // feature dim
#define WD 256     // word-embed dim
#define HD 512     // hidden dim
#define RTOT (TS*NS)   // 16320 output rows (r = t*64 + n)
#define RPAD 16384     // padded rows for hs

typedef __attribute__((ext_vector_type(4))) float f32x4;
typedef __attribute__((ext_vector_type(8))) short s16x8;
typedef __attribute__((ext_vector_type(4))) unsigned int u32x4;
typedef __attribute__((ext_vector_type(8))) int i32x8;

__device__ __forceinline__ unsigned short f2bf(float f){
  unsigned u; __builtin_memcpy(&u, &f, 4);
  u += 0x7FFFu + ((u >> 16) & 1u);            // RNE
  return (unsigned short)(u >> 16);
}
__device__ __forceinline__ float bf2f(unsigned short h){
  unsigned u = ((unsigned)h) << 16; float f; __builtin_memcpy(&f, &u, 4); return f;
}
__device__ __forceinline__ unsigned char f2fp8(float f){
  int p = __builtin_amdgcn_cvt_pk_fp8_f32(f, f, 0, false);  // OCP e4m3
  return (unsigned char)(p & 0xFF);
}
__device__ __forceinline__ float dot4_fp8(unsigned int a, unsigned int b){
  float d;
  d  = __builtin_amdgcn_cvt_f32_fp8(a, 0) * __builtin_amdgcn_cvt_f32_fp8(b, 0);
  d += __builtin_amdgcn_cvt_f32_fp8(a, 1) * __builtin_amdgcn_cvt_f32_fp8(b, 1);
  d += __builtin_amdgcn_cvt_f32_fp8(a, 2) * __builtin_amdgcn_cvt_f32_fp8(b, 2);
  d += __builtin_amdgcn_cvt_f32_fp8(a, 3) * __builtin_amdgcn_cvt_f32_fp8(b, 3);
  return d;
}
// MX-scaled MFMA, fp8 x fp8, unit scales -> exact fp8 GEMM at 2x rate (verified r6-r9, absmax 0.0)
__device__ __forceinline__ f32x4 mfma128(i32x8 a, i32x8 b, f32x4 c){
  return __builtin_amdgcn_mfma_scale_f32_16x16x128_f8f6f4(a, b, c, 0, 0, 0, 127, 0, 127);
}

// ---------------- fused K0: all weight/input conversions in ONE kernel.
// block ranges: [0,640) W_proj transpose | [640,768) Wx transpose | [768,1792) WhS
// [1792,6800) W_out transpose fp8 | [6800,7120) feat cvt | [7120,17120) Wembb cvt
__device__ __forceinline__ void transpose_cvt_blk(const float* __restrict__ src,
    unsigned char* __restrict__ dst, int R, int C, int bx, int by, int fp8, int tid){
  __shared__ float tile[32][33];
  int r0 = bx*32, c0 = by*32;
  int tr = tid >> 5, tc = tid & 31;
  #pragma unroll
  for(int p=0;p<4;p++){
    int r = r0 + tr + p*8, c = c0 + tc;
    tile[tr + p*8][tc] = (r < R && c < C) ? src[r*C + c] : 0.f;
  }
  __syncthreads();
  #pragma unroll
  for(int p=0;p<4;p++){
    int oc = c0 + tr + p*8;
    int orow = r0 + tc;
    if(oc < C && orow < R){
      float v = tile[tc][tr + p*8];
      if(fp8) dst[oc*R + orow] = f2fp8(v);
      else ((unsigned short*)dst)[oc*R + orow] = f2bf(v);
    }
  }
}

__global__ __launch_bounds__(256) void k_conv(const float* __restrict__ W_proj,
    const float* __restrict__ Wx, const float* __restrict__ Wh,
    const float* __restrict__ W_out, const float* __restrict__ feat,
    const float* __restrict__ W_embed,
    unsigned short* __restrict__ WprojT, unsigned short* __restrict__ WxT,
    unsigned char* __restrict__ Wh8S, unsigned char* __restrict__ WoutT,
    unsigned short* __restrict__ featb, unsigned short* __restrict__ Wembb,
    float* __restrict__ out0){
  int b = blockIdx.x, tid = threadIdx.x;
  if(b == 0 && tid == 0) out0[0] = 0.f;       // zero loss accumulator (stream-ordered)
  if(b < 640){
    transpose_cvt_blk(W_proj, (unsigned char*)WprojT, 1280, 512, b%40, b/40, 0, tid);
  } else if(b < 768){
    int bb = b - 640;
    transpose_cvt_blk(Wx, (unsigned char*)WxT, 256, 512, bb%8, bb/8, 0, tid);
  } else if(b < 1792){
    int i = (b-768)*256 + tid;                 // Wh -> wave-order K=128-frag fp8
    int blk = i>>11;
    int w = blk>>4, ct = (blk>>2)&3, kq = blk&3;
    int lane = (i>>5)&63, ib = i&31;
    int q = lane>>4, rr = lane&15;
    int k = kq*128 + q*32 + ib;
    int j = w*64 + ct*16 + rr;
    Wh8S[i] = f2fp8(Wh[k*HD + j]);
  } else if(b < 6800){
    int bb = b - 1792;
    transpose_cvt_blk(W_out, WoutT, 512, 10000, bb%16, bb/16, 1, tid);
  } else if(b < 7120){
    int i = (b-6800)*256 + tid;
    if(i < 64*DF) featb[i] = f2bf(feat[i]);
  } else {
    int i = (b-7120)*256 + tid;
    if(i < VV*WD) Wembb[i] = f2bf(W_embed[i]);
  }
}

// ---------------- K1: h0 = feat @ W_proj + b_proj  -> bf16 [64][512]
__global__ __launch_bounds__(256) void k_h0(const unsigned short* __restrict__ featb,
    const unsigned short* __restrict__ WprojT, const float* __restrict__ b_proj,
    unsigned short* __restrict__ h0b){
  __shared__ unsigned short Al[64*264];
  __shared__ unsigned short Bl[64*264];
  int tid = threadIdx.x, cb = blockIdx.x;
  int w = tid>>6, lane = tid&63, q = lane>>4, rr = lane&15;
  f32x4 acc[4];
  #pragma unroll
  for(int i=0;i<4;i++){ acc[i][0]=0.f; acc[i][1]=0.f; acc[i][2]=0.f; acc[i][3]=0.f; }
  for(int kb=0; kb<5; kb++){
    {
      int row = tid >> 2, part = tid & 3;
      const u32x4* s = (const u32x4*)(featb + row*DF + kb*256 + part*64);
      u32x4* d = (u32x4*)(Al + row*264 + part*64);
      #pragma unroll
      for(int i=0;i<8;i++) d[i] = s[i];
    }
    {
      int row = tid >> 2, part = tid & 3;
      int j = cb*64 + row;
      const u32x4* s = (const u32x4*)(WprojT + j*DF + kb*256 + part*64);
      u32x4* d = (u32x4*)(Bl + row*264 + part*64);
      #pragma unroll
      for(int i=0;i<8;i++) d[i] = s[i];
    }
    __syncthreads();
    #pragma unroll
    for(int kc=0;kc<8;kc++){
      s16x8 a = *(const s16x8*)(Al + (w*16 + rr)*264 + kc*32 + q*8);
      #pragma unroll
      for(int tc=0;tc<4;tc++){
        s16x8 bb = *(const s16x8*)(Bl + (tc*16 + rr)*264 + kc*32 + q*8);
        acc[tc] = __builtin_amdgcn_mfma_f32_16x16x32_bf16(a, bb, acc[tc], 0, 0, 0);
      }
    }
    __syncthreads();
  }
  #pragma unroll
  for(int tc=0;tc<4;tc++){
    #pragma unroll
    for(int reg=0;reg<4;reg++){
      int n = w*16 + q*4 + reg;
      int j = cb*64 + tc*16 + rr;
      h0b[n*HD + j] = f2bf(acc[tc][reg] + b_proj[j]);
    }
  }
}

// ---------------- K2: xW + b -> xWk in K3-thread-major layout.
__global__ __launch_bounds__(256) void k_xw(const unsigned short* __restrict__ Wembb,
    const unsigned short* __restrict__ WxT, const float* __restrict__ bvec,
    const int* __restrict__ captions, unsigned short* __restrict__ xWk){
  __shared__ unsigned short Al[64*264];
  __shared__ unsigned short Bl[64*264];
  int tid = threadIdx.x, cb = blockIdx.x, t = blockIdx.y;
  int w = tid>>6, lane = tid&63, q = lane>>4, rr = lane&15;
  {
    int row = tid >> 2, part = tid & 3;
    int idx = captions[row*TT + t];
    const u32x4* s = (const u32x4*)(Wembb + idx*WD + part*64);
    u32x4* d = (u32x4*)(Al + row*264 + part*64);
    #pragma unroll
    for(int i=0;i<8;i++) d[i] = s[i];
  }
  {
    int row = tid >> 2, part = tid & 3;
    int j = cb*64 + row;
    const u32x4* s = (const u32x4*)(WxT + j*WD + part*64);
    u32x4* d = (u32x4*)(Bl + row*264 + part*64);
    #pragma unroll
    for(int i=0;i<8;i++) d[i] = s[i];
  }
  __syncthreads();
  f32x4 acc[4];
  #pragma unroll
  for(int i=0;i<4;i++){ acc[i][0]=0.f; acc[i][1]=0.f; acc[i][2]=0.f; acc[i][3]=0.f; }
  #pragma unroll
  for(int kc=0;kc<8;kc++){
    s16x8 a = *(const s16x8*)(Al + (w*16 + rr)*264 + kc*32 + q*8);
    #pragma unroll
    for(int tc=0;tc<4;tc++){
      s16x8 bb = *(const s16x8*)(Bl + (tc*16 + rr)*264 + kc*32 + q*8);
      acc[tc] = __builtin_amdgcn_mfma_f32_16x16x32_bf16(a, bb, acc[tc], 0, 0, 0);
    }
  }
  #pragma unroll
  for(int tc=0;tc<4;tc++){
    int j = cb*64 + tc*16 + rr;
    float bo = bvec[j];
    unsigned short st[4];
    #pragma unroll
    for(int reg=0;reg<4;reg++)
      st[reg] = f2bf(acc[tc][reg] + bo);
    size_t f = (((size_t)t*4 + w)*8 + cb)*1024 + q*256 + rr*16 + tc*4;
    unsigned long v; __builtin_memcpy(&v, st, 8);
    *(unsigned long*)(xWk + f) = v;
  }
}

// ---------------- K3: RNN scan, K=128 MX MFMA. Round-7 proven body (374.5 us):
// wb[16] "preload" the compiler turns into a coalesced in-loop stream. VGPR 100.
__global__ __launch_bounds__(512, 2) void k_rnn(const unsigned short* __restrict__ h0b,
    const unsigned char* __restrict__ Wh8S, const unsigned short* __restrict__ xWk,
    unsigned char* __restrict__ hs8){
  __shared__ unsigned char hbuf[2][16*560];    // fp8 h, stride 560
  int tid = threadIdx.x, w = tid>>6, lane = tid&63, q = lane>>4, rr = lane&15;
  int n0 = blockIdx.x * 16;
  int j0 = w * 64;
  i32x8 wb[16];
  #pragma unroll
  for(int ct=0;ct<4;ct++)
    #pragma unroll
    for(int kq=0;kq<4;kq++)
      wb[ct*4+kq] = *(const i32x8*)(Wh8S + (size_t)((w*4+ct)*4+kq)*2048 + lane*32);
  {
    int s = tid>>5, c0 = (tid&31)*16;
    #pragma unroll
    for(int i=0;i<16;i++)
      hbuf[0][s*560 + c0 + i] = f2fp8(bf2f(h0b[(n0+s)*HD + c0 + i]));
  }
  __syncthreads();
  int scp = tid>>5, scc = (tid&31)*16;
  const unsigned short* xp = xWk + (((size_t)blockIdx.x)*8 + w)*1024 + q*256 + rr*16;
  for(int t=0; t<TS; t++){
    const unsigned char* hb = hbuf[t&1];
    unsigned char*       hn = hbuf[(t&1)^1];
    if(t)
      *(u32x4*)(hs8 + (size_t)((t-1)*NS + n0 + scp)*HD + scc) = *(const u32x4*)(hb + scp*560 + scc);
    unsigned short xs[16];
    *(u32x4*)(xs)   = *(const u32x4*)(xp);
    *(u32x4*)(xs+8) = *(const u32x4*)(xp+8);
    i32x8 af[4];
    #pragma unroll
    for(int kq=0;kq<4;kq++)
      af[kq] = *(const i32x8*)(hb + rr*560 + kq*128 + q*32);
    f32x4 acc[4];
    #pragma unroll
    for(int ct=0;ct<4;ct++){ acc[ct][0]=0.f; acc[ct][1]=0.f; acc[ct][2]=0.f; acc[ct][3]=0.f; }
    #pragma unroll
    for(int ct=0;ct<4;ct++)
      #pragma unroll
      for(int kq=0;kq<4;kq++)
        acc[ct] = mfma128(af[kq], wb[ct*4+kq], acc[ct]);
    #pragma unroll
    for(int ct=0;ct<4;ct++){
      int j = j0 + ct*16 + rr;
      #pragma unroll
      for(int reg=0;reg<4;reg++){
        int nl = q*4 + reg;
        float pre = acc[ct][reg] + bf2f(xs[ct*4+reg]);
        float e2 = __builtin_amdgcn_exp2f(pre * 2.8853900817779268f); // e^(2x)
        float h = (e2 - 1.f) * __builtin_amdgcn_rcpf(e2 + 1.f);       // tanh
        hn[nl*560 + j] = f2fp8(h);
      }
    }
    __syncthreads();
    xp += 32768;
  }
  *(u32x4*)(hs8 + (size_t)((TS-1)*NS + n0 + scp)*HD + scc) = *(const u32x4*)(hbuf[TS&1] + scp*560 + scc);
}

// ---------------- K4: fused scores GEMM + sumexp partials. Round-1 proven (132.6 us).
__global__ __launch_bounds__(256, 2) void k_scores(const unsigned char* __restrict__ hs8,
    const unsigned char* __restrict__ WoutT, const float* __restrict__ b_out,
    float* __restrict__ partial_s){
  __shared__ unsigned char Bl[128*528];
  __shared__ float sred[2][128];
  int tid = threadIdx.x;
  int chunk = blockIdx.x, rb = blockIdx.y;
  int w = tid>>6, lane = tid&63, q = lane>>4, rr = lane&15;
  int wi = w>>1, wj = w&1;
  long af[4][16];
  #pragma unroll
  for(int tr=0;tr<4;tr++)
    #pragma unroll
    for(int kc=0;kc<16;kc++){
      int row = rb*128 + wi*64 + tr*16 + rr;   // < RPAD always
      af[tr][kc] = *(const long*)(hs8 + (size_t)row*HD + kc*32 + q*8);
    }
  float sacc[16];
  #pragma unroll
  for(int i=0;i<16;i++) sacc[i]=0.f;
  int vc0 = chunk*2500, vc1 = vc0 + 2500;
  for(int vt=0; vt<20; vt++){
    int vbase = vc0 + vt*128;
    {
      int v = tid>>1, half = tid&1;
      int vg = vbase + v; if(vg > VV-1) vg = VV-1;
      const u32x4* s = (const u32x4*)(WoutT + (size_t)vg*HD + half*256);
      u32x4* d = (u32x4*)(Bl + v*528 + half*256);
      #pragma unroll
      for(int i=0;i<16;i++) d[i] = s[i];
    }
    __syncthreads();
    f32x4 acc[4][4];
    #pragma unroll
    for(int a=0;a<4;a++)
      #pragma unroll
      for(int b=0;b<4;b++){ acc[a][b][0]=0.f; acc[a][b][1]=0.f; acc[a][b][2]=0.f; acc[a][b][3]=0.f; }
    #pragma unroll
    for(int kc=0;kc<16;kc++){
      long bf[4];
      #pragma unroll
      for(int tc=0;tc<4;tc++)
        bf[tc] = *(const long*)(Bl + (wj*64 + tc*16 + rr)*528 + kc*32 + q*8);
      #pragma unroll
      for(int tr=0;tr<4;tr++)
        #pragma unroll
        for(int tc=0;tc<4;tc++)
          acc[tr][tc] = __builtin_amdgcn_mfma_f32_16x16x32_fp8_fp8(af[tr][kc], bf[tc], acc[tr][tc], 0, 0, 0);
    }
    #pragma unroll
    for(int tc=0;tc<4;tc++){
      int vg = vbase + wj*64 + tc*16 + rr;
      bool vok = vg < vc1;
      float bo = vok ? b_out[vg] : 0.f;
      #pragma unroll
      for(int tr=0;tr<4;tr++)
        #pragma unroll
        for(int reg=0;reg<4;reg++){
          float sc = acc[tr][tc][reg] + bo;
          float ex = __builtin_amdgcn_exp2f(sc * 1.4426950408889634f);
          if(vok) sacc[tr*4+reg] += ex;
        }
    }
    __syncthreads();
  }
  #pragma unroll
  for(int i=0;i<16;i++){
    float v = sacc[i];
    v += __shfl_xor(v, 1, 64);
    v += __shfl_xor(v, 2, 64);
    v += __shfl_xor(v, 4, 64);
    v += __shfl_xor(v, 8, 64);
    sacc[i] = v;
  }
  if(rr == 0){
    #pragma unroll
    for(int tr=0;tr<4;tr++)
      #pragma unroll
      for(int reg=0;reg<4;reg++)
        sred[wj][wi*64 + tr*16 + q*4 + reg] = sacc[tr*4+reg];
  }
  __syncthreads();
  if(tid < 128){
    int row = rb*128 + tid;
    if(row < RTOT) partial_s[row*4 + chunk] = sred[0][tid] + sred[1][tid];
  }
}

// ---------------- K5: merged picked + loss. One wave per row; per-block partial
// loss summed and atomicAdd'ed into out[0] (zeroed by k_conv earlier in-stream).
__global__ __launch_bounds__(256) void k_pickedloss(const unsigned char* __restrict__ hs8,
    const unsigned char* __restrict__ WoutT, const float* __restrict__ b_out,
    const int* __restrict__ captions, const float* __restrict__ partial_s,
    float* __restrict__ out){
  int tid = threadIdx.x;
  int w = tid>>6, lane = tid&63;
  int R = blockIdx.x*4 + w;                 // 4080*4 = 16320 exact
  int t = R >> 6, n = R & 63;
  int y = captions[n*TT + t + 1];
  const unsigned int* hp = (const unsigned int*)(hs8 + (size_t)R*HD + lane*8);
  const unsigned int* wp = (const unsigned int*)(WoutT + (size_t)y*HD + lane*8);
  unsigned int hv0 = hp[0], hv1 = hp[1], wv0 = wp[0], wv1 = wp[1];
  float d = dot4_fp8(hv0, wv0) + dot4_fp8(hv1, wv1);
  d += __shfl_xor(d, 1, 64);
  d += __shfl_xor(d, 2, 64);
  d += __shfl_xor(d, 4, 64);
  d += __shfl_xor(d, 8, 64);
  d += __shfl_xor(d, 16, 64);
  d += __shfl_xor(d, 32, 64);
  __shared__ float red[4];
  if(lane == 0){
    float contrib = 0.f;
    if(y != 0){
      float picked = d + b_out[y];
      float s = partial_s[R*4] + partial_s[R*4+1] + partial_s[R*4+2] + partial_s[R*4+3];
      contrib = __logf(s) - picked;
    }
    red[w] = contrib;
  }
  __syncthreads();
  if(tid == 0){
    float v = (red[0]+red[1]+red[2]+red[3]) * (1.0f/64.0f);
    atomicAdd(out, v);
  }
}

extern "C" void kernel_launch(void* const* d_in, const int* in_sizes, int n_in,
                              void* d_out, int out_size, void* d_ws, size_t ws_size,
                              hipStream_t stream) {
  const float* feat    = (const float*)d_in[0];
  const float* W_proj  = (const float*)d_in[1];
  const float* b_proj  = (const float*)d_in[2];
  const float* W_embed = (const float*)d_in[3];
  const float* Wx      = (const float*)d_in[4];
  const float* Wh      = (const float*)d_in[5];
  const float* bvec    = (const float*)d_in[6];
  const float* W_out   = (const float*)d_in[7];
  const float* b_out   = (const float*)d_in[8];
  const int*   captions= (const int*)d_in[9];

  char* p = (char*)d_ws;
  unsigned short* WprojT = (unsigned short*)p;  p += 512*1280*2;
  unsigned short* WxT    = (unsigned short*)p;  p += 512*256*2;
  unsigned char*  Wh8S   = (unsigned char*)p;   p += 512*512;
  unsigned char*  WoutT  = (unsigned char*)p;   p += 10000*512;
  unsigned short* Wembb  = (unsigned short*)p;  p += 10000*256*2;
  unsigned short* featb  = (unsigned short*)p;  p += 64*1280*2;
  unsigned short* h0b    = (unsigned short*)p;  p += 64*512*2;
  unsigned short* xWk    = (unsigned short*)p;  p += TS*64*512*2;
  unsigned char*  hs8    = (unsigned char*)p;   p += RPAD*512;
  float* partial_s       = (float*)p;           p += RTOT*4*4;
  if((size_t)(p - (char*)d_ws) > ws_size) return;

  // fused conversions (+ zero out[0])
  k_conv<<<17120, 256, 0, stream>>>(W_proj, Wx, Wh, W_out, feat, W_embed,
                                    WprojT, WxT, Wh8S, WoutT, featb, Wembb,
                                    (float*)d_out);
  k_h0<<<8, 256, 0, stream>>>(featb, WprojT, b_proj, h0b);
  k_xw<<<dim3(8, TS), 256, 0, stream>>>(Wembb, WxT, bvec, captions, xWk);
  k_rnn<<<4, 512, 0, stream>>>(h0b, Wh8S, xWk, hs8);
  k_scores<<<dim3(4, 128), 256, 0, stream>>>(hs8, WoutT, b_out, partial_s);
  k_pickedloss<<<4080, 256, 0, stream>>>(hs8, WoutT, b_out, captions, partial_s, (float*)d_out);
}